// Round 8
// baseline (615.530 us; speedup 1.0000x reference)
//
#include <hip/hip_runtime.h>
#include <hip/hip_bf16.h>

#define NV 64
#define NP 32
#define NM 16
#define VMED 4000
#define EMB 256
#define EMBFF 128
#define MAXNNZ 512

// NOTE (hard-won, rounds 0-7): ALL float inputs and the output are FP32.
// The reference's jax arrays are default float32; misreading them as bf16
// gives parity-dependent mantissa garbage (diagnosed via the R5/R7-NaN vs
// R6-pass signature). Do not "optimize" these casts back to bf16.

// ---- block-wide LDS tree reductions (fully synced) ----
__device__ __forceinline__ float block_sum_256(float v, float* red) {
    int t = threadIdx.x;
    red[t] = v; __syncthreads();
    for (int s = 128; s > 0; s >>= 1) { if (t < s) red[t] += red[t + s]; __syncthreads(); }
    float r = red[0]; __syncthreads();
    return r;
}
__device__ __forceinline__ float block_max_256(float v, float* red) {
    int t = threadIdx.x;
    red[t] = v; __syncthreads();
    for (int s = 128; s > 0; s >>= 1) { if (t < s) red[t] = fmaxf(red[t], red[t + s]); __syncthreads(); }
    float r = red[0]; __syncthreads();
    return r;
}

// K1: i2 = relu(conv1d(mean(emb_table[proc_codes], axis=1)))  -- 128 threads/visit
__global__ void k_embed_conv(const int* __restrict__ proc, const float* __restrict__ emb,
                             const float* __restrict__ cw, const float* __restrict__ cb,
                             float* __restrict__ i2) {
    __shared__ float sm[EMBFF + 2];
    int v = blockIdx.x, f = threadIdx.x;
    float s = 0.f;
    for (int c = 0; c < NP; c++) {
        int code = proc[v * NP + c];
        s += emb[code * EMBFF + f];
    }
    sm[f + 1] = s * (1.0f / NP);
    if (f == 0) { sm[0] = 0.f; sm[EMBFF + 1] = 0.f; }
    __syncthreads();
    float o = cw[0] * sm[f] + cw[1] * sm[f + 1] + cw[2] * sm[f + 2] + cb[0];
    i2[v * EMBFF + f] = o > 0.f ? o : 0.f;
}

// K2: q,k,v = i2 @ wq/wk/wv ; qaw = q * softmax(q*alpha*scale)  -- 256 threads/visit
__global__ void k_qkv(const float* __restrict__ i2, const float* __restrict__ wq,
                      const float* __restrict__ wk, const float* __restrict__ wv,
                      const float* __restrict__ alpha,
                      float* __restrict__ q, float* __restrict__ k, float* __restrict__ v,
                      float* __restrict__ qaw) {
    __shared__ float x[EMBFF];
    __shared__ float red[256];
    int vi = blockIdx.x, f = threadIdx.x;
    if (f < EMBFF) x[f] = i2[vi * EMBFF + f];
    __syncthreads();
    float aq = 0, ak = 0, av = 0;
    for (int e = 0; e < EMBFF; e++) {
        float xe = x[e];
        aq += xe * wq[e * EMB + f];
        ak += xe * wk[e * EMB + f];
        av += xe * wv[e * EMB + f];
    }
    q[vi * EMB + f] = aq; k[vi * EMB + f] = ak; v[vi * EMB + f] = av;
    const float scale = 0.0625f;  // 256^-0.5
    float z = aq * alpha[f] * scale;
    float m = block_max_256(z, red);
    float e_ = __expf(z - m);
    float sum = block_sum_256(e_, red);
    qaw[vi * EMB + f] = aq * (e_ / sum);
}

// K3/K5: column sum over visits
__global__ void k_colsum(const float* __restrict__ a, float* __restrict__ out, int rows) {
    int f = threadIdx.x;  // 256
    float s = 0;
    for (int r = 0; r < rows; r++) s += a[r * EMB + f];
    out[f] = s;
}

// K4: p = gq*k (per row), pbw = p * softmax(p*beta*scale)
__global__ void k_pbw(const float* __restrict__ gq, const float* __restrict__ k,
                      const float* __restrict__ beta, float* __restrict__ pbw) {
    __shared__ float red[256];
    int vi = blockIdx.x, f = threadIdx.x;
    float p = gq[f] * k[vi * EMB + f];
    const float scale = 0.0625f;
    float z = p * beta[f] * scale;
    float m = block_max_256(z, red);
    float e_ = __expf(z - m);
    float sum = block_sum_256(e_, red);
    pbw[vi * EMB + f] = p * (e_ / sum);
}

// K6: feat = (gk * v) @ wr + q
__global__ void k_feat(const float* __restrict__ gk, const float* __restrict__ v,
                       const float* __restrict__ q, const float* __restrict__ wr,
                       float* __restrict__ feat) {
    __shared__ float s[EMB];
    int vi = blockIdx.x, f = threadIdx.x;  // 256
    s[f] = gk[f] * v[vi * EMB + f];
    __syncthreads();
    float acc = 0;
    for (int e = 0; e < EMB; e++) acc += s[e] * wr[e * EMB + f];
    feat[vi * EMB + f] = acc + q[vi * EMB + f];
}

// K7: visit_w = softmax(query @ history_keys.T) over 63 visits -- 64 threads, LDS tree
__global__ void k_visitw(const float* __restrict__ feat, float* __restrict__ visit_w) {
    __shared__ float qs[EMB];
    __shared__ float red[64];
    int t = threadIdx.x;  // 64
    for (int e = t; e < EMB; e += 64) qs[e] = feat[63 * EMB + e];
    __syncthreads();
    float sc = -1e30f;
    if (t < 63) {
        float a = 0;
        for (int e = 0; e < EMB; e++) a += qs[e] * feat[t * EMB + e];
        sc = a;
    }
    red[t] = sc; __syncthreads();
    for (int s = 32; s > 0; s >>= 1) { if (t < s) red[t] = fmaxf(red[t], red[t + s]); __syncthreads(); }
    float m = red[0]; __syncthreads();
    float e_ = (t < 63) ? __expf(sc - m) : 0.f;
    red[t] = e_; __syncthreads();
    for (int s = 32; s > 0; s >>= 1) { if (t < s) red[t] += red[t + s]; __syncthreads(); }
    float sum = red[0]; __syncthreads();
    if (t < 63) visit_w[t] = e_ / sum;
}

// K8: w_med = visit_w @ hv (hv one-hot with SET semantics -> dedup within a visit)
__global__ void k_wmed(const int* __restrict__ med, const float* __restrict__ visit_w,
                       float* __restrict__ w_med) {
    __shared__ float wm[VMED];
    int t = threadIdx.x;  // 256
    for (int i = t; i < VMED; i += 256) wm[i] = 0.f;
    __syncthreads();
    for (int i = t; i < 63 * NM; i += 256) {
        int v = i / NM, m = i % NM;
        int code = med[v * NM + m];
        bool dup = false;
        for (int mm = 0; mm < m; mm++)
            if (med[v * NM + mm] == code) dup = true;
        if (!dup) atomicAdd(&wm[code], visit_w[v]);  // LDS atomic
    }
    __syncthreads();
    for (int i = t; i < VMED; i += 256) w_med[i] = wm[i];
}

// K9: h = relu(adj @ w1 + b1), sparse scan of adj row (~41 nnz incl diagonal)
__global__ void k_spmm_relu(const float* __restrict__ adj, const float* __restrict__ w1,
                            const float* __restrict__ b1, float* __restrict__ h) {
    __shared__ int idx[MAXNNZ];
    __shared__ float val[MAXNNZ];
    __shared__ int cnt;
    int i = blockIdx.x, t = threadIdx.x;  // 256
    if (t == 0) cnt = 0;
    __syncthreads();
    const float* row = adj + (size_t)i * VMED;
    for (int j = t; j < VMED; j += 256) {
        float a = row[j];
        if (a != 0.f) {
            int p = atomicAdd(&cnt, 1);  // LDS atomic
            if (p < MAXNNZ) { idx[p] = j; val[p] = a; }
        }
    }
    __syncthreads();
    int n = cnt < MAXNNZ ? cnt : MAXNNZ;
    float acc = b1[t];
    for (int e = 0; e < n; e++) acc += val[e] * w1[idx[e] * EMB + t];
    h[(size_t)i * EMB + t] = acc > 0.f ? acc : 0.f;
}

// K10: x = x @ w2 (in-place safe: block i stages row i in LDS before writing row i)
__global__ void k_rowgemm(const float* __restrict__ h, const float* __restrict__ w2,
                          float* __restrict__ out) {
    __shared__ float x[EMB];
    int i = blockIdx.x, f = threadIdx.x;  // 256
    x[f] = h[(size_t)i * EMB + f];
    __syncthreads();
    float acc = 0;
    for (int e = 0; e < EMB; e++) acc += x[e] * w2[e * EMB + f];
    out[(size_t)i * EMB + f] = acc;
}

// K11: mode 0: dm = adj @ x + b2 ; mode 1: dm -= inter*(adj @ x + b2)
__global__ void k_spmm_acc(const float* __restrict__ adj, const float* __restrict__ x,
                           const float* __restrict__ b2, const float* __restrict__ inter,
                           int mode, float* __restrict__ dm) {
    __shared__ int idx[MAXNNZ];
    __shared__ float val[MAXNNZ];
    __shared__ int cnt;
    int i = blockIdx.x, t = threadIdx.x;  // 256
    if (t == 0) cnt = 0;
    __syncthreads();
    const float* row = adj + (size_t)i * VMED;
    for (int j = t; j < VMED; j += 256) {
        float a = row[j];
        if (a != 0.f) {
            int p = atomicAdd(&cnt, 1);  // LDS atomic
            if (p < MAXNNZ) { idx[p] = j; val[p] = a; }
        }
    }
    __syncthreads();
    int n = cnt < MAXNNZ ? cnt : MAXNNZ;
    float acc = b2[t];
    for (int e = 0; e < n; e++) acc += val[e] * x[(size_t)idx[e] * EMB + t];
    if (mode == 0) dm[(size_t)i * EMB + t] = acc;
    else           dm[(size_t)i * EMB + t] -= inter[0] * acc;
}

// K12: s_dm[i] = dot(query, dm[i])  -- one row per block, 256 threads
__global__ void k_scores(const float* __restrict__ dm, const float* __restrict__ feat,
                         float* __restrict__ s_dm) {
    __shared__ float red[256];
    int i = blockIdx.x, t = threadIdx.x;
    float s = dm[(size_t)i * EMB + t] * feat[63 * EMB + t];
    s = block_sum_256(s, red);
    if (t == 0) s_dm[i] = s;
}

// K13: key_w1 = softmax(s_dm) over 4000 (single block, 256 threads)
__global__ void k_softmax4000(const float* __restrict__ s, float* __restrict__ out) {
    __shared__ float red[256];
    int t = threadIdx.x;
    float m = -1e30f;
    for (int i = t; i < VMED; i += 256) m = fmaxf(m, s[i]);
    m = block_max_256(m, red);
    float sum = 0;
    for (int i = t; i < VMED; i += 256) { float e = __expf(s[i] - m); out[i] = e; sum += e; }
    sum = block_sum_256(sum, red);
    float inv = 1.f / sum;
    for (int i = t; i < VMED; i += 256) out[i] *= inv;
}

// K14: per-block partials of fact1 = key_w1 @ dm, fact2 = w_med @ dm. 16 blocks x 250 rows.
__global__ void k_facts_part(const float* __restrict__ dm, const float* __restrict__ kw,
                             const float* __restrict__ wm, float* __restrict__ part1,
                             float* __restrict__ part2) {
    int f = threadIdx.x;  // 256
    int b = blockIdx.x;
    int r0 = b * 250;
    float a1 = 0, a2 = 0;
    for (int r = r0; r < r0 + 250; r++) {
        float d = dm[(size_t)r * EMB + f];
        a1 += kw[r] * d;
        a2 += wm[r] * d;
    }
    part1[b * EMB + f] = a1;
    part2[b * EMB + f] = a2;
}

// K15: hidden = relu([query,fact1,fact2] @ out_w1 + out_b1)  (768 -> 512)
__global__ void k_hidden(const float* __restrict__ feat, const float* __restrict__ part1,
                         const float* __restrict__ part2, const float* __restrict__ w1,
                         const float* __restrict__ b1, float* __restrict__ hidden) {
    __shared__ float x[3 * EMB];
    int t = threadIdx.x;  // 256
    x[t] = feat[63 * EMB + t];
    float s1 = 0, s2 = 0;
    for (int b = 0; b < 16; b++) { s1 += part1[b * EMB + t]; s2 += part2[b * EMB + t]; }
    x[EMB + t] = s1; x[2 * EMB + t] = s2;
    __syncthreads();
    for (int o = 0; o < 2; o++) {
        int j = o * 256 + t;
        float acc = b1[j];
        for (int e = 0; e < 3 * EMB; e++) acc += x[e] * w1[e * 512 + j];
        hidden[j] = acc > 0.f ? acc : 0.f;
    }
}

// K16: result = hidden @ out_w2 + out_b2 ; fp32 out ; sp = sigmoid(result)
__global__ void k_result(const float* __restrict__ hidden, const float* __restrict__ w2,
                         const float* __restrict__ b2, float* __restrict__ out,
                         float* __restrict__ sp) {
    __shared__ float hx[512];
    int t = threadIdx.x;  // 256
    hx[t] = hidden[t]; hx[256 + t] = hidden[256 + t];
    __syncthreads();
    int j = blockIdx.x * 256 + t;
    if (j >= VMED) return;
    float acc = b2[j];
    for (int e = 0; e < 512; e++) acc += hx[e] * w2[(size_t)e * VMED + j];
    out[j] = acc;
    sp[j] = 1.f / (1.f + __expf(-acc));
}

// K17: bpart[i] = sp[i] * (ddi_raw[i,:] . sp)  -- one row per block
__global__ void k_bneg(const float* __restrict__ ddi, const float* __restrict__ sp,
                       float* __restrict__ bpart) {
    __shared__ float red[256];
    int i = blockIdx.x, t = threadIdx.x;
    const float* row = ddi + (size_t)i * VMED;
    float p = 0;
    for (int j = t; j < VMED; j += 256) p += row[j] * sp[j];
    p = block_sum_256(p, red);
    if (t == 0) bpart[i] = sp[i] * p;
}

// K18: batch_neg = 0.0005 * sum(bpart) -> out[4000] (fp32)
__global__ void FastRx_wo_Diag_19473381720179_kernel(const float* __restrict__ bpart,
                                                     float* __restrict__ out) {
    __shared__ float red[256];
    int t = threadIdx.x;  // 256
    float s = 0;
    for (int i = t; i < VMED; i += 256) s += bpart[i];
    s = block_sum_256(s, red);
    if (t == 0) out[VMED] = 0.0005f * s;
}

extern "C" __attribute__((visibility("default")))
void kernel_launch(void* const* d_in, const int* in_sizes, int n_in,
                   void* d_out, int out_size, void* d_ws, size_t ws_size,
                   hipStream_t stream) {
    const int*   proc_codes = (const int*)d_in[0];
    const int*   med_codes  = (const int*)d_in[1];
    const float* emb_table  = (const float*)d_in[2];
    const float* conv_w     = (const float*)d_in[3];
    const float* conv_b     = (const float*)d_in[4];
    const float* wq         = (const float*)d_in[5];
    const float* wk         = (const float*)d_in[6];
    const float* wv         = (const float*)d_in[7];
    const float* wr         = (const float*)d_in[8];
    const float* alpha      = (const float*)d_in[9];
    const float* beta       = (const float*)d_in[10];
    const float* ehr_adj    = (const float*)d_in[11];
    const float* ddi_adj    = (const float*)d_in[12];
    const float* ddi_raw    = (const float*)d_in[13];
    const float* ehr_w1     = (const float*)d_in[14];
    const float* ehr_b1     = (const float*)d_in[15];
    const float* ehr_w2     = (const float*)d_in[16];
    const float* ehr_b2     = (const float*)d_in[17];
    const float* ddi_w1     = (const float*)d_in[18];
    const float* ddi_b1     = (const float*)d_in[19];
    const float* ddi_w2     = (const float*)d_in[20];
    const float* ddi_b2     = (const float*)d_in[21];
    const float* inter      = (const float*)d_in[22];
    const float* out_w1     = (const float*)d_in[23];
    const float* out_b1     = (const float*)d_in[24];
    const float* out_w2     = (const float*)d_in[25];
    const float* out_b2     = (const float*)d_in[26];
    float* out = (float*)d_out;   // fp32: result[4000] ++ batch_neg[1]

    float* w = (float*)d_ws;
    float* i2     = w;                  // 8192
    float* q      = i2 + 8192;          // 16384
    float* k      = q + 16384;          // 16384
    float* v      = k + 16384;          // 16384
    float* tmp    = v + 16384;          // 16384 (qaw then pbw)
    float* feat   = tmp + 16384;        // 16384
    float* gq     = feat + 16384;       // 256
    float* gk     = gq + 256;           // 256
    float* visitw = gk + 256;           // 64
    float* wmed   = visitw + 64;        // 4000
    float* sdm    = wmed + 4000;        // 4000
    float* keyw   = sdm + 4000;         // 4000
    float* hidden = keyw + 4000;        // 512
    float* sp     = hidden + 512;       // 4000
    float* part1  = sp + 4000;          // 4096
    float* part2  = part1 + 4096;       // 4096
    float* bpart  = part2 + 4096;       // 4096
    float* bufA   = bpart + 4096;       // 1,024,000 (GCN working buffer)
    float* bufB   = bufA + 1024000;     // 1,024,000 (drug_memory)
    // total ~8.7 MB

    k_embed_conv<<<NV, EMBFF, 0, stream>>>(proc_codes, emb_table, conv_w, conv_b, i2);
    k_qkv<<<NV, EMB, 0, stream>>>(i2, wq, wk, wv, alpha, q, k, v, tmp);
    k_colsum<<<1, EMB, 0, stream>>>(tmp, gq, NV);
    k_pbw<<<NV, EMB, 0, stream>>>(gq, k, beta, tmp);
    k_colsum<<<1, EMB, 0, stream>>>(tmp, gk, NV);
    k_feat<<<NV, EMB, 0, stream>>>(gk, v, q, wr, feat);
    k_visitw<<<1, 64, 0, stream>>>(feat, visitw);
    k_wmed<<<1, 256, 0, stream>>>(med_codes, visitw, wmed);

    // EHR GCN: h -> bufA (in-place h@w2) -> dm(bufB)
    k_spmm_relu<<<VMED, 256, 0, stream>>>(ehr_adj, ehr_w1, ehr_b1, bufA);
    k_rowgemm<<<VMED, 256, 0, stream>>>(bufA, ehr_w2, bufA);
    k_spmm_acc<<<VMED, 256, 0, stream>>>(ehr_adj, bufA, ehr_b2, inter, 0, bufB);
    // DDI GCN: bufB -= inter * (...)
    k_spmm_relu<<<VMED, 256, 0, stream>>>(ddi_adj, ddi_w1, ddi_b1, bufA);
    k_rowgemm<<<VMED, 256, 0, stream>>>(bufA, ddi_w2, bufA);
    k_spmm_acc<<<VMED, 256, 0, stream>>>(ddi_adj, bufA, ddi_b2, inter, 1, bufB);

    k_scores<<<VMED, 256, 0, stream>>>(bufB, feat, sdm);
    k_softmax4000<<<1, 256, 0, stream>>>(sdm, keyw);
    k_facts_part<<<16, 256, 0, stream>>>(bufB, keyw, wmed, part1, part2);
    k_hidden<<<1, 256, 0, stream>>>(feat, part1, part2, out_w1, out_b1, hidden);
    k_result<<<16, 256, 0, stream>>>(hidden, out_w2, out_b2, out, sp);
    k_bneg<<<VMED, 256, 0, stream>>>(ddi_raw, sp, bpart);
    FastRx_wo_Diag_19473381720179_kernel<<<1, 256, 0, stream>>>(bpart, out);
}

// Round 9
// 521.433 us; speedup vs baseline: 1.1805x; 1.1805x over previous
//
#include <hip/hip_runtime.h>
#include <hip/hip_bf16.h>

#define NV 64
#define NP 32
#define NM 16
#define VMED 4000
#define EMB 256
#define EMBFF 128
#define MAXNNZ 512

// NOTE (hard-won, rounds 0-7): ALL float inputs and the output are FP32.
// Misreading them as bf16 gives parity-dependent mantissa garbage. Do not
// "optimize" these casts back to bf16.

// ---- block-wide LDS tree reductions (fully synced) ----
__device__ __forceinline__ float block_sum_256(float v, float* red) {
    int t = threadIdx.x;
    red[t] = v; __syncthreads();
    for (int s = 128; s > 0; s >>= 1) { if (t < s) red[t] += red[t + s]; __syncthreads(); }
    float r = red[0]; __syncthreads();
    return r;
}
__device__ __forceinline__ float block_max_256(float v, float* red) {
    int t = threadIdx.x;
    red[t] = v; __syncthreads();
    for (int s = 128; s > 0; s >>= 1) { if (t < s) red[t] = fmaxf(red[t], red[t + s]); __syncthreads(); }
    float r = red[0]; __syncthreads();
    return r;
}

// K1: i2 = relu(conv1d(mean(emb_table[proc_codes], axis=1)))  -- 128 threads/visit
__global__ void k_embed_conv(const int* __restrict__ proc, const float* __restrict__ emb,
                             const float* __restrict__ cw, const float* __restrict__ cb,
                             float* __restrict__ i2) {
    __shared__ float sm[EMBFF + 2];
    int v = blockIdx.x, f = threadIdx.x;
    float s = 0.f;
    for (int c = 0; c < NP; c++) {
        int code = proc[v * NP + c];
        s += emb[code * EMBFF + f];
    }
    sm[f + 1] = s * (1.0f / NP);
    if (f == 0) { sm[0] = 0.f; sm[EMBFF + 1] = 0.f; }
    __syncthreads();
    float o = cw[0] * sm[f] + cw[1] * sm[f + 1] + cw[2] * sm[f + 2] + cb[0];
    i2[v * EMBFF + f] = o > 0.f ? o : 0.f;
}

// K2: q,k,v = i2 @ wq/wk/wv ; qaw = q * softmax(q*alpha*scale)  -- 256 threads/visit
__global__ void k_qkv(const float* __restrict__ i2, const float* __restrict__ wq,
                      const float* __restrict__ wk, const float* __restrict__ wv,
                      const float* __restrict__ alpha,
                      float* __restrict__ q, float* __restrict__ k, float* __restrict__ v,
                      float* __restrict__ qaw) {
    __shared__ float x[EMBFF];
    __shared__ float red[256];
    int vi = blockIdx.x, f = threadIdx.x;
    if (f < EMBFF) x[f] = i2[vi * EMBFF + f];
    __syncthreads();
    float aq = 0, ak = 0, av = 0;
    for (int e = 0; e < EMBFF; e++) {
        float xe = x[e];
        aq += xe * wq[e * EMB + f];
        ak += xe * wk[e * EMB + f];
        av += xe * wv[e * EMB + f];
    }
    q[vi * EMB + f] = aq; k[vi * EMB + f] = ak; v[vi * EMB + f] = av;
    const float scale = 0.0625f;  // 256^-0.5
    float z = aq * alpha[f] * scale;
    float m = block_max_256(z, red);
    float e_ = __expf(z - m);
    float sum = block_sum_256(e_, red);
    qaw[vi * EMB + f] = aq * (e_ / sum);
}

// K3/K5: column sum over visits
__global__ void k_colsum(const float* __restrict__ a, float* __restrict__ out, int rows) {
    int f = threadIdx.x;  // 256
    float s = 0;
    for (int r = 0; r < rows; r++) s += a[r * EMB + f];
    out[f] = s;
}

// K4: p = gq*k (per row), pbw = p * softmax(p*beta*scale)
__global__ void k_pbw(const float* __restrict__ gq, const float* __restrict__ k,
                      const float* __restrict__ beta, float* __restrict__ pbw) {
    __shared__ float red[256];
    int vi = blockIdx.x, f = threadIdx.x;
    float p = gq[f] * k[vi * EMB + f];
    const float scale = 0.0625f;
    float z = p * beta[f] * scale;
    float m = block_max_256(z, red);
    float e_ = __expf(z - m);
    float sum = block_sum_256(e_, red);
    pbw[vi * EMB + f] = p * (e_ / sum);
}

// K6: feat = (gk * v) @ wr + q
__global__ void k_feat(const float* __restrict__ gk, const float* __restrict__ v,
                       const float* __restrict__ q, const float* __restrict__ wr,
                       float* __restrict__ feat) {
    __shared__ float s[EMB];
    int vi = blockIdx.x, f = threadIdx.x;  // 256
    s[f] = gk[f] * v[vi * EMB + f];
    __syncthreads();
    float acc = 0;
    for (int e = 0; e < EMB; e++) acc += s[e] * wr[e * EMB + f];
    feat[vi * EMB + f] = acc + q[vi * EMB + f];
}

// K7: visit_w = softmax(query @ history_keys.T) over 63 visits -- 64 threads
__global__ void k_visitw(const float* __restrict__ feat, float* __restrict__ visit_w) {
    __shared__ float qs[EMB];
    __shared__ float red[64];
    int t = threadIdx.x;  // 64
    for (int e = t; e < EMB; e += 64) qs[e] = feat[63 * EMB + e];
    __syncthreads();
    float sc = -1e30f;
    if (t < 63) {
        float a = 0;
        for (int e = 0; e < EMB; e++) a += qs[e] * feat[t * EMB + e];
        sc = a;
    }
    red[t] = sc; __syncthreads();
    for (int s = 32; s > 0; s >>= 1) { if (t < s) red[t] = fmaxf(red[t], red[t + s]); __syncthreads(); }
    float m = red[0]; __syncthreads();
    float e_ = (t < 63) ? __expf(sc - m) : 0.f;
    red[t] = e_; __syncthreads();
    for (int s = 32; s > 0; s >>= 1) { if (t < s) red[t] += red[t + s]; __syncthreads(); }
    float sum = red[0]; __syncthreads();
    if (t < 63) visit_w[t] = e_ / sum;
}

// K8: w_med = visit_w @ hv (hv one-hot with SET semantics -> dedup within a visit)
__global__ void k_wmed(const int* __restrict__ med, const float* __restrict__ visit_w,
                       float* __restrict__ w_med) {
    __shared__ float wm[VMED];
    int t = threadIdx.x;  // 256
    for (int i = t; i < VMED; i += 256) wm[i] = 0.f;
    __syncthreads();
    for (int i = t; i < 63 * NM; i += 256) {
        int v = i / NM, m = i % NM;
        int code = med[v * NM + m];
        bool dup = false;
        for (int mm = 0; mm < m; mm++)
            if (med[v * NM + mm] == code) dup = true;
        if (!dup) atomicAdd(&wm[code], visit_w[v]);  // LDS atomic
    }
    __syncthreads();
    for (int i = t; i < VMED; i += 256) w_med[i] = wm[i];
}

// ---- float4 sparse row scan -> LDS (idx,val) compaction ----
__device__ __forceinline__ int scan_row4(const float* __restrict__ adj, int i,
                                         int* idx, float* val, int* cnt) {
    int t = threadIdx.x;
    if (t == 0) *cnt = 0;
    __syncthreads();
    const float4* row4 = (const float4*)(adj + (size_t)i * VMED);
    for (int j4 = t; j4 < VMED / 4; j4 += 256) {
        float4 a = row4[j4];
        if (a.x != 0.f) { int p = atomicAdd(cnt, 1); if (p < MAXNNZ) { idx[p] = 4*j4+0; val[p] = a.x; } }
        if (a.y != 0.f) { int p = atomicAdd(cnt, 1); if (p < MAXNNZ) { idx[p] = 4*j4+1; val[p] = a.y; } }
        if (a.z != 0.f) { int p = atomicAdd(cnt, 1); if (p < MAXNNZ) { idx[p] = 4*j4+2; val[p] = a.z; } }
        if (a.w != 0.f) { int p = atomicAdd(cnt, 1); if (p < MAXNNZ) { idx[p] = 4*j4+3; val[p] = a.w; } }
    }
    __syncthreads();
    int n = *cnt;
    return n < MAXNNZ ? n : MAXNNZ;
}

// K9: h = relu(adj @ w1 + b1), sparse scan of adj row (~41 nnz incl diagonal)
__global__ void k_spmm_relu(const float* __restrict__ adj, const float* __restrict__ w1,
                            const float* __restrict__ b1, float* __restrict__ h) {
    __shared__ int idx[MAXNNZ];
    __shared__ float val[MAXNNZ];
    __shared__ int cnt;
    int i = blockIdx.x, t = threadIdx.x;  // 256
    int n = scan_row4(adj, i, idx, val, &cnt);
    float acc = b1[t];
    for (int e = 0; e < n; e++) acc += val[e] * w1[idx[e] * EMB + t];
    h[(size_t)i * EMB + t] = acc > 0.f ? acc : 0.f;
}

// K10: x = x @ w2, 8 rows per block (in-place safe: rows staged in LDS first)
__global__ void k_rowgemm(const float* __restrict__ h, const float* __restrict__ w2,
                          float* __restrict__ out) {
    __shared__ float x[8][EMB];
    int r0 = blockIdx.x * 8, t = threadIdx.x;  // 500 blocks x 256
    for (int r = 0; r < 8; r++) x[r][t] = h[(size_t)(r0 + r) * EMB + t];
    __syncthreads();
    float acc[8] = {0, 0, 0, 0, 0, 0, 0, 0};
    #pragma unroll 4
    for (int e = 0; e < EMB; e++) {
        float we = w2[e * EMB + t];
        #pragma unroll
        for (int r = 0; r < 8; r++) acc[r] += x[r][e] * we;
    }
    for (int r = 0; r < 8; r++) out[(size_t)(r0 + r) * EMB + t] = acc[r];
}

// K11: mode 0: dm = adj @ x + b2 ; mode 1: dm -= inter*(adj @ x + b2)
__global__ void k_spmm_acc(const float* __restrict__ adj, const float* __restrict__ x,
                           const float* __restrict__ b2, const float* __restrict__ inter,
                           int mode, float* __restrict__ dm) {
    __shared__ int idx[MAXNNZ];
    __shared__ float val[MAXNNZ];
    __shared__ int cnt;
    int i = blockIdx.x, t = threadIdx.x;  // 256
    int n = scan_row4(adj, i, idx, val, &cnt);
    float acc = b2[t];
    for (int e = 0; e < n; e++) acc += val[e] * x[(size_t)idx[e] * EMB + t];
    if (mode == 0) dm[(size_t)i * EMB + t] = acc;
    else           dm[(size_t)i * EMB + t] -= inter[0] * acc;
}

// K12: s_dm[i] = dot(query, dm[i])  -- one row per block, 256 threads
__global__ void k_scores(const float* __restrict__ dm, const float* __restrict__ feat,
                         float* __restrict__ s_dm) {
    __shared__ float red[256];
    int i = blockIdx.x, t = threadIdx.x;
    float s = dm[(size_t)i * EMB + t] * feat[63 * EMB + t];
    s = block_sum_256(s, red);
    if (t == 0) s_dm[i] = s;
}

// K13: key_w1 = softmax(s_dm) over 4000 (single block; in-place safe)
__global__ void k_softmax4000(const float* __restrict__ s, float* __restrict__ out) {
    __shared__ float red[256];
    int t = threadIdx.x;
    float m = -1e30f;
    for (int i = t; i < VMED; i += 256) m = fmaxf(m, s[i]);
    m = block_max_256(m, red);
    float sum = 0;
    for (int i = t; i < VMED; i += 256) { float e = __expf(s[i] - m); out[i] = e; sum += e; }
    sum = block_sum_256(sum, red);
    float inv = 1.f / sum;
    for (int i = t; i < VMED; i += 256) out[i] *= inv;
}

// K14: partials of fact1 = key_w1 @ dm, fact2 = w_med @ dm. 40 blocks x 100 rows.
__global__ void k_facts_part(const float* __restrict__ dm, const float* __restrict__ kw,
                             const float* __restrict__ wm, float* __restrict__ part1,
                             float* __restrict__ part2) {
    int f = threadIdx.x;  // 256
    int b = blockIdx.x;
    int r0 = b * 100;
    float a1 = 0, a2 = 0;
    for (int r = r0; r < r0 + 100; r++) {
        float d = dm[(size_t)r * EMB + f];
        a1 += kw[r] * d;
        a2 += wm[r] * d;
    }
    part1[b * EMB + f] = a1;
    part2[b * EMB + f] = a2;
}

// K15: K-partitioned hidden matvec: hpart[b][j] = sum_{e in chunk b} x[e]*w1[e*512+j]
// x = [query(feat row 63), fact1(sum part1), fact2(sum part2)], 48 blocks x 16 e-rows.
__global__ void k_hidden_part(const float* __restrict__ feat, const float* __restrict__ part1,
                              const float* __restrict__ part2, const float* __restrict__ w1,
                              float* __restrict__ hpart) {
    __shared__ float xs[16];
    int b = blockIdx.x, t = threadIdx.x;  // 48 x 256
    int e0 = b * 16;
    if (t < 16) {
        int e = e0 + t;
        float xv;
        if (e < 256) {
            xv = feat[63 * EMB + e];
        } else if (e < 512) {
            float s = 0;
            for (int p = 0; p < 40; p++) s += part1[p * EMB + (e - 256)];
            xv = s;
        } else {
            float s = 0;
            for (int p = 0; p < 40; p++) s += part2[p * EMB + (e - 512)];
            xv = s;
        }
        xs[t] = xv;
    }
    __syncthreads();
    float a1 = 0, a2 = 0;
    #pragma unroll
    for (int i = 0; i < 16; i++) {
        int e = e0 + i;
        a1 += xs[i] * w1[e * 512 + t];
        a2 += xs[i] * w1[e * 512 + t + 256];
    }
    hpart[b * 512 + t] = a1;
    hpart[b * 512 + t + 256] = a2;
}

// K16: hidden = relu(sum hpart + b1); result = hidden @ out_w2 + out_b2 (fp32 out);
//      sp = sigmoid(result). 63 blocks x 64 threads (one output column per thread).
__global__ void k_result(const float* __restrict__ hpart, const float* __restrict__ b1,
                         const float* __restrict__ w2, const float* __restrict__ b2,
                         float* __restrict__ out, float* __restrict__ sp) {
    __shared__ float hx[512];
    int t = threadIdx.x;  // 64
    for (int jj = t; jj < 512; jj += 64) {
        float s = b1[jj];
        for (int p = 0; p < 48; p++) s += hpart[p * 512 + jj];
        hx[jj] = s > 0.f ? s : 0.f;
    }
    __syncthreads();
    int j = blockIdx.x * 64 + t;
    if (j >= VMED) return;
    float acc = b2[j];
    for (int e = 0; e < 512; e++) acc += hx[e] * w2[(size_t)e * VMED + j];
    out[j] = acc;
    sp[j] = 1.f / (1.f + __expf(-acc));
}

// K17: bpart[i] = sp[i] * (ddi_raw[i,:] . sp) -- one row per block, float4 + LDS sp
__global__ void k_bneg(const float* __restrict__ ddi, const float* __restrict__ sp,
                       float* __restrict__ bpart) {
    __shared__ float4 spl[VMED / 4];
    __shared__ float red[256];
    int i = blockIdx.x, t = threadIdx.x;
    const float4* sp4 = (const float4*)sp;
    for (int j4 = t; j4 < VMED / 4; j4 += 256) spl[j4] = sp4[j4];
    __syncthreads();
    const float4* row4 = (const float4*)(ddi + (size_t)i * VMED);
    float p = 0;
    for (int j4 = t; j4 < VMED / 4; j4 += 256) {
        float4 a = row4[j4];
        float4 s4 = spl[j4];
        p += a.x * s4.x + a.y * s4.y + a.z * s4.z + a.w * s4.w;
    }
    p = block_sum_256(p, red);
    if (t == 0) bpart[i] = sp[i] * p;
}

// K18: batch_neg = 0.0005 * sum(bpart) -> out[4000] (fp32)
__global__ void FastRx_wo_Diag_19473381720179_kernel(const float* __restrict__ bpart,
                                                     float* __restrict__ out) {
    __shared__ float red[256];
    int t = threadIdx.x;  // 256
    float s = 0;
    for (int i = t; i < VMED; i += 256) s += bpart[i];
    s = block_sum_256(s, red);
    if (t == 0) out[VMED] = 0.0005f * s;
}

extern "C" __attribute__((visibility("default")))
void kernel_launch(void* const* d_in, const int* in_sizes, int n_in,
                   void* d_out, int out_size, void* d_ws, size_t ws_size,
                   hipStream_t stream) {
    const int*   proc_codes = (const int*)d_in[0];
    const int*   med_codes  = (const int*)d_in[1];
    const float* emb_table  = (const float*)d_in[2];
    const float* conv_w     = (const float*)d_in[3];
    const float* conv_b     = (const float*)d_in[4];
    const float* wq         = (const float*)d_in[5];
    const float* wk         = (const float*)d_in[6];
    const float* wv         = (const float*)d_in[7];
    const float* wr         = (const float*)d_in[8];
    const float* alpha      = (const float*)d_in[9];
    const float* beta       = (const float*)d_in[10];
    const float* ehr_adj    = (const float*)d_in[11];
    const float* ddi_adj    = (const float*)d_in[12];
    const float* ddi_raw    = (const float*)d_in[13];
    const float* ehr_w1     = (const float*)d_in[14];
    const float* ehr_b1     = (const float*)d_in[15];
    const float* ehr_w2     = (const float*)d_in[16];
    const float* ehr_b2     = (const float*)d_in[17];
    const float* ddi_w1     = (const float*)d_in[18];
    const float* ddi_b1     = (const float*)d_in[19];
    const float* ddi_w2     = (const float*)d_in[20];
    const float* ddi_b2     = (const float*)d_in[21];
    const float* inter      = (const float*)d_in[22];
    const float* out_w1     = (const float*)d_in[23];
    const float* out_b1     = (const float*)d_in[24];
    const float* out_w2     = (const float*)d_in[25];
    const float* out_b2     = (const float*)d_in[26];
    float* out = (float*)d_out;   // fp32: result[4000] ++ batch_neg[1]

    float* w = (float*)d_ws;      // all offsets multiples of 256 floats (16B-aligned)
    float* i2     = w;                  // 8192
    float* q      = w + 8192;           // 16384
    float* k      = w + 24576;          // 16384
    float* v      = w + 40960;          // 16384
    float* tmp    = w + 57344;          // 16384 (qaw then pbw)
    float* feat   = w + 73728;          // 16384
    float* gq     = w + 90112;          // 256
    float* gk     = w + 90368;          // 256
    float* visitw = w + 90624;          // 256 (64 used)
    float* wmed   = w + 90880;          // 4096
    float* sdm    = w + 94976;          // 4096 (softmax in-place -> key_w1)
    float* sp     = w + 99072;          // 4096
    float* bufA   = w + 103168;         // 1,024,000 (GCN h / h@w2; dead after ddi spmm_acc)
    float* bufB   = bufA + 1024000;     // 1,024,000 (drug_memory)
    // aliases into dead bufA (first use is AFTER the last read of bufA):
    float* part1  = bufA;               // 40*256
    float* part2  = bufA + 10240;       // 40*256
    float* hpart  = bufA + 20480;       // 48*512
    float* bpart  = bufA + 45056;       // 4096
    // total ws: ~8.6 MB

    k_embed_conv<<<NV, EMBFF, 0, stream>>>(proc_codes, emb_table, conv_w, conv_b, i2);
    k_qkv<<<NV, EMB, 0, stream>>>(i2, wq, wk, wv, alpha, q, k, v, tmp);
    k_colsum<<<1, EMB, 0, stream>>>(tmp, gq, NV);
    k_pbw<<<NV, EMB, 0, stream>>>(gq, k, beta, tmp);
    k_colsum<<<1, EMB, 0, stream>>>(tmp, gk, NV);
    k_feat<<<NV, EMB, 0, stream>>>(gk, v, q, wr, feat);
    k_visitw<<<1, 64, 0, stream>>>(feat, visitw);
    k_wmed<<<1, 256, 0, stream>>>(med_codes, visitw, wmed);

    // EHR GCN: h -> bufA (in-place h@w2) -> dm(bufB)
    k_spmm_relu<<<VMED, 256, 0, stream>>>(ehr_adj, ehr_w1, ehr_b1, bufA);
    k_rowgemm<<<VMED / 8, 256, 0, stream>>>(bufA, ehr_w2, bufA);
    k_spmm_acc<<<VMED, 256, 0, stream>>>(ehr_adj, bufA, ehr_b2, inter, 0, bufB);
    // DDI GCN: bufB -= inter * (...)
    k_spmm_relu<<<VMED, 256, 0, stream>>>(ddi_adj, ddi_w1, ddi_b1, bufA);
    k_rowgemm<<<VMED / 8, 256, 0, stream>>>(bufA, ddi_w2, bufA);
    k_spmm_acc<<<VMED, 256, 0, stream>>>(ddi_adj, bufA, ddi_b2, inter, 1, bufB);

    k_scores<<<VMED, 256, 0, stream>>>(bufB, feat, sdm);
    k_softmax4000<<<1, 256, 0, stream>>>(sdm, sdm);
    k_facts_part<<<40, 256, 0, stream>>>(bufB, sdm, wmed, part1, part2);
    k_hidden_part<<<48, 256, 0, stream>>>(feat, part1, part2, out_w1, hpart);
    k_result<<<63, 64, 0, stream>>>(hpart, out_b1, out_w2, out_b2, out, sp);
    k_bneg<<<VMED, 256, 0, stream>>>(ddi_raw, sp, bpart);
    FastRx_wo_Diag_19473381720179_kernel<<<1, 256, 0, stream>>>(bpart, out);
}

// Round 10
// 456.285 us; speedup vs baseline: 1.3490x; 1.1428x over previous
//
#include <hip/hip_runtime.h>
#include <hip/hip_bf16.h>

#define NV 64
#define NP 32
#define NM 16
#define VMED 4000
#define EMB 256
#define EMBFF 128
#define CAP 128   // max cached nnz/row (mean ~41, 13 sigma headroom)

// NOTE (hard-won, rounds 0-7): ALL float inputs and the output are FP32.
// Misreading them as bf16 gives parity-dependent mantissa garbage. Do not
// "optimize" these casts back to bf16.

__device__ __forceinline__ float block_sum_256(float v, float* red) {
    int t = threadIdx.x;
    red[t] = v; __syncthreads();
    for (int s = 128; s > 0; s >>= 1) { if (t < s) red[t] += red[t + s]; __syncthreads(); }
    float r = red[0]; __syncthreads();
    return r;
}
__device__ __forceinline__ float block_max_256(float v, float* red) {
    int t = threadIdx.x;
    red[t] = v; __syncthreads();
    for (int s = 128; s > 0; s >>= 1) { if (t < s) red[t] = fmaxf(red[t], red[t + s]); __syncthreads(); }
    float r = red[0]; __syncthreads();
    return r;
}

// K1: i2 = relu(conv1d(mean(emb_table[proc_codes])))  -- 128 threads/visit
__global__ void k_embed_conv(const int* __restrict__ proc, const float* __restrict__ emb,
                             const float* __restrict__ cw, const float* __restrict__ cb,
                             float* __restrict__ i2) {
    __shared__ float sm[EMBFF + 2];
    int v = blockIdx.x, f = threadIdx.x;
    float s = 0.f;
    for (int c = 0; c < NP; c++) s += emb[proc[v * NP + c] * EMBFF + f];
    sm[f + 1] = s * (1.0f / NP);
    if (f == 0) { sm[0] = 0.f; sm[EMBFF + 1] = 0.f; }
    __syncthreads();
    float o = cw[0] * sm[f] + cw[1] * sm[f + 1] + cw[2] * sm[f + 2] + cb[0];
    i2[v * EMBFF + f] = o > 0.f ? o : 0.f;
}

// K2: q,k,v = i2 @ wq/wk/wv ; qaw = q * softmax(q*alpha*scale) -> tmpA
__global__ void k_qkv(const float* __restrict__ i2, const float* __restrict__ wq,
                      const float* __restrict__ wk, const float* __restrict__ wv,
                      const float* __restrict__ alpha,
                      float* __restrict__ q, float* __restrict__ k, float* __restrict__ v,
                      float* __restrict__ qaw) {
    __shared__ float x[EMBFF];
    __shared__ float red[256];
    int vi = blockIdx.x, f = threadIdx.x;
    if (f < EMBFF) x[f] = i2[vi * EMBFF + f];
    __syncthreads();
    float aq = 0, ak = 0, av = 0;
    for (int e = 0; e < EMBFF; e++) {
        float xe = x[e];
        aq += xe * wq[e * EMB + f];
        ak += xe * wk[e * EMB + f];
        av += xe * wv[e * EMB + f];
    }
    q[vi * EMB + f] = aq; k[vi * EMB + f] = ak; v[vi * EMB + f] = av;
    const float scale = 0.0625f;
    float z = aq * alpha[f] * scale;
    float m = block_max_256(z, red);
    float e_ = __expf(z - m);
    float sum = block_sum_256(e_, red);
    qaw[vi * EMB + f] = aq * (e_ / sum);
}

// K4: gq = colsum(qaw) computed inline; p = gq*k; pbw = p*softmax(p*beta*scale) -> tmpB
__global__ void k_pbw(const float* __restrict__ qaw, const float* __restrict__ k,
                      const float* __restrict__ beta, float* __restrict__ pbw) {
    __shared__ float red[256];
    int vi = blockIdx.x, f = threadIdx.x;
    float g = 0;
    for (int r = 0; r < NV; r++) g += qaw[r * EMB + f];
    float p = g * k[vi * EMB + f];
    const float scale = 0.0625f;
    float z = p * beta[f] * scale;
    float m = block_max_256(z, red);
    float e_ = __expf(z - m);
    float sum = block_sum_256(e_, red);
    pbw[vi * EMB + f] = p * (e_ / sum);
}

// K6: gk = colsum(pbw) inline; feat = (gk*v) @ wr + q
__global__ void k_feat(const float* __restrict__ pbw, const float* __restrict__ v,
                       const float* __restrict__ q, const float* __restrict__ wr,
                       float* __restrict__ feat) {
    __shared__ float s[EMB];
    int vi = blockIdx.x, f = threadIdx.x;
    float g = 0;
    for (int r = 0; r < NV; r++) g += pbw[r * EMB + f];
    s[f] = g * v[vi * EMB + f];
    __syncthreads();
    float acc = 0;
    for (int e = 0; e < EMB; e++) acc += s[e] * wr[e * EMB + f];
    feat[vi * EMB + f] = acc + q[vi * EMB + f];
}

// K7+K8 fused: visit_w = softmax(query @ hist.T); w_med = visit_w @ hv (dedup SET)
__global__ void k_visitw_wmed(const float* __restrict__ feat, const int* __restrict__ med,
                              float* __restrict__ w_med) {
    __shared__ float qs[EMB];
    __shared__ float vw[64];
    __shared__ float red[256];
    __shared__ float wm[VMED];
    int t = threadIdx.x;  // 256
    for (int e = t; e < EMB; e += 256) qs[e] = feat[63 * EMB + e];
    for (int i = t; i < VMED; i += 256) wm[i] = 0.f;
    __syncthreads();
    float sc = -1e30f;
    if (t < 63) {
        float a = 0;
        for (int e = 0; e < EMB; e++) a += qs[e] * feat[t * EMB + e];
        sc = a;
    }
    float m = block_max_256(sc, red);
    float e_ = (t < 63) ? __expf(sc - m) : 0.f;
    float sum = block_sum_256(e_, red);
    if (t < 63) vw[t] = e_ / sum;
    __syncthreads();
    for (int i = t; i < 63 * NM; i += 256) {
        int vv = i / NM, mm = i % NM;
        int code = med[vv * NM + mm];
        bool dup = false;
        for (int m2 = 0; m2 < mm; m2++)
            if (med[vv * NM + m2] == code) dup = true;
        if (!dup) atomicAdd(&wm[code], vw[vv]);  // LDS atomic
    }
    __syncthreads();
    for (int i = t; i < VMED; i += 256) w_med[i] = wm[i];
}

// K9: h = relu(adj @ w1 + b1) via float4 scan; ALSO caches the compacted row
// (cnt, idx, val) to global for reuse by k_spmm_acc (skips the 64 MB re-scan).
__global__ void k_spmm_relu(const float* __restrict__ adj, const float* __restrict__ w1,
                            const float* __restrict__ b1, float* __restrict__ h,
                            int* __restrict__ ccnt, int* __restrict__ cidx,
                            float* __restrict__ cval) {
    __shared__ int idx[CAP];
    __shared__ float val[CAP];
    __shared__ int cnt;
    int i = blockIdx.x, t = threadIdx.x;
    if (t == 0) cnt = 0;
    __syncthreads();
    const float4* row4 = (const float4*)(adj + (size_t)i * VMED);
    for (int j4 = t; j4 < VMED / 4; j4 += 256) {
        float4 a = row4[j4];
        if (a.x != 0.f) { int p = atomicAdd(&cnt, 1); if (p < CAP) { idx[p] = 4*j4+0; val[p] = a.x; } }
        if (a.y != 0.f) { int p = atomicAdd(&cnt, 1); if (p < CAP) { idx[p] = 4*j4+1; val[p] = a.y; } }
        if (a.z != 0.f) { int p = atomicAdd(&cnt, 1); if (p < CAP) { idx[p] = 4*j4+2; val[p] = a.z; } }
        if (a.w != 0.f) { int p = atomicAdd(&cnt, 1); if (p < CAP) { idx[p] = 4*j4+3; val[p] = a.w; } }
    }
    __syncthreads();
    int n = cnt < CAP ? cnt : CAP;
    if (t == 0) ccnt[i] = n;
    if (t < n) { cidx[i * CAP + t] = idx[t]; cval[i * CAP + t] = val[t]; }
    float acc = b1[t];
    for (int e = 0; e < n; e++) acc += val[e] * w1[idx[e] * EMB + t];
    h[(size_t)i * EMB + t] = acc > 0.f ? acc : 0.f;
}

// K10: x = x @ w2, 8 rows per block (in-place safe: rows staged in LDS first)
__global__ void k_rowgemm(const float* __restrict__ h, const float* __restrict__ w2,
                          float* __restrict__ out) {
    __shared__ float x[8][EMB];
    int r0 = blockIdx.x * 8, t = threadIdx.x;
    for (int r = 0; r < 8; r++) x[r][t] = h[(size_t)(r0 + r) * EMB + t];
    __syncthreads();
    float acc[8] = {0, 0, 0, 0, 0, 0, 0, 0};
    #pragma unroll 4
    for (int e = 0; e < EMB; e++) {
        float we = w2[e * EMB + t];
        #pragma unroll
        for (int r = 0; r < 8; r++) acc[r] += x[r][e] * we;
    }
    for (int r = 0; r < 8; r++) out[(size_t)(r0 + r) * EMB + t] = acc[r];
}

// K11: uses cached CSR (no adjacency re-scan).
// mode 0: dm = adj@x + b2 ; mode 1: dm -= inter*(adj@x + b2)
__global__ void k_spmm_acc(const int* __restrict__ ccnt, const int* __restrict__ cidx,
                           const float* __restrict__ cval, const float* __restrict__ x,
                           const float* __restrict__ b2, const float* __restrict__ inter,
                           int mode, float* __restrict__ dm) {
    __shared__ int idx[CAP];
    __shared__ float val[CAP];
    int i = blockIdx.x, t = threadIdx.x;
    int n = ccnt[i];
    if (t < n) { idx[t] = cidx[i * CAP + t]; val[t] = cval[i * CAP + t]; }
    __syncthreads();
    float acc = b2[t];
    for (int e = 0; e < n; e++) acc += val[e] * x[(size_t)idx[e] * EMB + t];
    if (mode == 0) dm[(size_t)i * EMB + t] = acc;
    else           dm[(size_t)i * EMB + t] -= inter[0] * acc;
}

// K12: s_dm[i] = dot(query, dm[i])
__global__ void k_scores(const float* __restrict__ dm, const float* __restrict__ feat,
                         float* __restrict__ s_dm) {
    __shared__ float red[256];
    int i = blockIdx.x, t = threadIdx.x;
    float s = dm[(size_t)i * EMB + t] * feat[63 * EMB + t];
    s = block_sum_256(s, red);
    if (t == 0) s_dm[i] = s;
}

// K13: softmax over 4000 (in-place safe)
__global__ void k_softmax4000(const float* __restrict__ s, float* __restrict__ out) {
    __shared__ float red[256];
    int t = threadIdx.x;
    float m = -1e30f;
    for (int i = t; i < VMED; i += 256) m = fmaxf(m, s[i]);
    m = block_max_256(m, red);
    float sum = 0;
    for (int i = t; i < VMED; i += 256) { float e = __expf(s[i] - m); out[i] = e; sum += e; }
    sum = block_sum_256(sum, red);
    float inv = 1.f / sum;
    for (int i = t; i < VMED; i += 256) out[i] *= inv;
}

// K14: partials of fact1 = key_w1 @ dm, fact2 = w_med @ dm. 40 blocks x 100 rows.
__global__ void k_facts_part(const float* __restrict__ dm, const float* __restrict__ kw,
                             const float* __restrict__ wm, float* __restrict__ part1,
                             float* __restrict__ part2) {
    int f = threadIdx.x, b = blockIdx.x;
    int r0 = b * 100;
    float a1 = 0, a2 = 0;
    for (int r = r0; r < r0 + 100; r++) {
        float d = dm[(size_t)r * EMB + f];
        a1 += kw[r] * d;
        a2 += wm[r] * d;
    }
    part1[b * EMB + f] = a1;
    part2[b * EMB + f] = a2;
}

// K15: K-partitioned hidden matvec (48 blocks x 16 e-rows of out_w1)
__global__ void k_hidden_part(const float* __restrict__ feat, const float* __restrict__ part1,
                              const float* __restrict__ part2, const float* __restrict__ w1,
                              float* __restrict__ hpart) {
    __shared__ float xs[16];
    int b = blockIdx.x, t = threadIdx.x;
    int e0 = b * 16;
    if (t < 16) {
        int e = e0 + t;
        float xv;
        if (e < 256) xv = feat[63 * EMB + e];
        else if (e < 512) { float s = 0; for (int p = 0; p < 40; p++) s += part1[p * EMB + (e - 256)]; xv = s; }
        else              { float s = 0; for (int p = 0; p < 40; p++) s += part2[p * EMB + (e - 512)]; xv = s; }
        xs[t] = xv;
    }
    __syncthreads();
    float a1 = 0, a2 = 0;
    #pragma unroll
    for (int i = 0; i < 16; i++) {
        int e = e0 + i;
        a1 += xs[i] * w1[e * 512 + t];
        a2 += xs[i] * w1[e * 512 + t + 256];
    }
    hpart[b * 512 + t] = a1;
    hpart[b * 512 + t + 256] = a2;
}

// K16: hidden = relu(sum hpart + b1); result = hidden @ out_w2 + out_b2; sp = sigmoid.
// 125 blocks x 256: 32 columns/block, 8-way K-split per column, LDS reduce.
__global__ void k_result(const float* __restrict__ hpart, const float* __restrict__ b1,
                         const float* __restrict__ w2, const float* __restrict__ b2,
                         float* __restrict__ out, float* __restrict__ sp) {
    __shared__ float hx[512];
    __shared__ float red[8][32];
    int t = threadIdx.x;
    for (int jj = t; jj < 512; jj += 256) {
        float s = b1[jj];
        for (int p = 0; p < 48; p++) s += hpart[p * 512 + jj];
        hx[jj] = s > 0.f ? s : 0.f;
    }
    __syncthreads();
    int lane = t & 31, seg = t >> 5;          // 8 segs x 64 e's each
    int j = blockIdx.x * 32 + lane;           // 125*32 = 4000
    float acc = 0;
    int e0 = seg * 64;
    #pragma unroll 8
    for (int e = e0; e < e0 + 64; e++) acc += hx[e] * w2[(size_t)e * VMED + j];
    red[seg][lane] = acc;
    __syncthreads();
    if (seg == 0) {
        float s = b2[j];
        for (int p = 0; p < 8; p++) s += red[p][lane];
        out[j] = s;
        sp[j] = 1.f / (1.f + __expf(-s));
    }
}

// K17: bpart[i] = sp[i] * (ddi_raw[i,:] . sp) -- 8 rows/block, float4 + LDS sp
__global__ void k_bneg(const float* __restrict__ ddi, const float* __restrict__ sp,
                       float* __restrict__ bpart) {
    __shared__ float4 spl[VMED / 4];
    __shared__ float red[256];
    int t = threadIdx.x;
    const float4* sp4 = (const float4*)sp;
    for (int j4 = t; j4 < VMED / 4; j4 += 256) spl[j4] = sp4[j4];
    __syncthreads();
    for (int rr = 0; rr < 8; rr++) {
        int i = blockIdx.x * 8 + rr;
        const float4* row4 = (const float4*)(ddi + (size_t)i * VMED);
        float p = 0;
        for (int j4 = t; j4 < VMED / 4; j4 += 256) {
            float4 a = row4[j4];
            float4 s4 = spl[j4];
            p += a.x * s4.x + a.y * s4.y + a.z * s4.z + a.w * s4.w;
        }
        p = block_sum_256(p, red);
        if (t == 0) bpart[i] = sp[i] * p;
    }
}

// K18: batch_neg = 0.0005 * sum(bpart) -> out[4000]
__global__ void FastRx_wo_Diag_19473381720179_kernel(const float* __restrict__ bpart,
                                                     float* __restrict__ out) {
    __shared__ float red[256];
    int t = threadIdx.x;
    float s = 0;
    for (int i = t; i < VMED; i += 256) s += bpart[i];
    s = block_sum_256(s, red);
    if (t == 0) out[VMED] = 0.0005f * s;
}

extern "C" __attribute__((visibility("default")))
void kernel_launch(void* const* d_in, const int* in_sizes, int n_in,
                   void* d_out, int out_size, void* d_ws, size_t ws_size,
                   hipStream_t stream) {
    const int*   proc_codes = (const int*)d_in[0];
    const int*   med_codes  = (const int*)d_in[1];
    const float* emb_table  = (const float*)d_in[2];
    const float* conv_w     = (const float*)d_in[3];
    const float* conv_b     = (const float*)d_in[4];
    const float* wq         = (const float*)d_in[5];
    const float* wk         = (const float*)d_in[6];
    const float* wv         = (const float*)d_in[7];
    const float* wr         = (const float*)d_in[8];
    const float* alpha      = (const float*)d_in[9];
    const float* beta       = (const float*)d_in[10];
    const float* ehr_adj    = (const float*)d_in[11];
    const float* ddi_adj    = (const float*)d_in[12];
    const float* ddi_raw    = (const float*)d_in[13];
    const float* ehr_w1     = (const float*)d_in[14];
    const float* ehr_b1     = (const float*)d_in[15];
    const float* ehr_w2     = (const float*)d_in[16];
    const float* ehr_b2     = (const float*)d_in[17];
    const float* ddi_w1     = (const float*)d_in[18];
    const float* ddi_b1     = (const float*)d_in[19];
    const float* ddi_w2     = (const float*)d_in[20];
    const float* ddi_b2     = (const float*)d_in[21];
    const float* inter      = (const float*)d_in[22];
    const float* out_w1     = (const float*)d_in[23];
    const float* out_b1     = (const float*)d_in[24];
    const float* out_w2     = (const float*)d_in[25];
    const float* out_b2     = (const float*)d_in[26];
    float* out = (float*)d_out;   // fp32: result[4000] ++ batch_neg[1]

    float* w = (float*)d_ws;      // offsets 16B-aligned
    float* i2     = w;                  // 8192
    float* q      = w + 8192;           // 16384
    float* k      = w + 24576;          // 16384
    float* v      = w + 40960;          // 16384
    float* tmpA   = w + 57344;          // 16384 (qaw)
    float* tmpB   = w + 73728;          // 16384 (pbw)
    float* feat   = w + 90112;          // 16384
    float* wmed   = w + 106496;         // 4096
    float* sdm    = w + 110592;         // 4096 (softmax in-place -> key_w1)
    float* sp     = w + 114688;         // 4096
    float* bufA   = w + 118784;         // 1,024,000 (GCN h / h@w2)
    float* bufB   = bufA + 1024000;     // 1,024,000 (drug_memory)
    int*   ccnt   = (int*)(bufB + 1024000);   // 4096
    int*   cidx   = ccnt + 4096;              // 4000*128 = 512000
    float* cval   = (float*)(cidx + 512000);  // 512000
    // aliases into dead bufA (first written AFTER last read of bufA):
    float* part1  = bufA;               // 40*256
    float* part2  = bufA + 10240;       // 40*256
    float* hpart  = bufA + 20480;       // 48*512
    float* bpart  = bufA + 45056;       // 4096
    // total ws ~16.8 MB (ws_size = 256 MiB per round-9 poison profile)

    k_embed_conv<<<NV, EMBFF, 0, stream>>>(proc_codes, emb_table, conv_w, conv_b, i2);
    k_qkv<<<NV, EMB, 0, stream>>>(i2, wq, wk, wv, alpha, q, k, v, tmpA);
    k_pbw<<<NV, EMB, 0, stream>>>(tmpA, k, beta, tmpB);
    k_feat<<<NV, EMB, 0, stream>>>(tmpB, v, q, wr, feat);
    k_visitw_wmed<<<1, 256, 0, stream>>>(feat, med_codes, wmed);

    // EHR GCN: scan+CSR-cache -> rowgemm (in-place) -> acc via CSR
    k_spmm_relu<<<VMED, 256, 0, stream>>>(ehr_adj, ehr_w1, ehr_b1, bufA, ccnt, cidx, cval);
    k_rowgemm<<<VMED / 8, 256, 0, stream>>>(bufA, ehr_w2, bufA);
    k_spmm_acc<<<VMED, 256, 0, stream>>>(ccnt, cidx, cval, bufA, ehr_b2, inter, 0, bufB);
    // DDI GCN (reuses CSR buffers)
    k_spmm_relu<<<VMED, 256, 0, stream>>>(ddi_adj, ddi_w1, ddi_b1, bufA, ccnt, cidx, cval);
    k_rowgemm<<<VMED / 8, 256, 0, stream>>>(bufA, ddi_w2, bufA);
    k_spmm_acc<<<VMED, 256, 0, stream>>>(ccnt, cidx, cval, bufA, ddi_b2, inter, 1, bufB);

    k_scores<<<VMED, 256, 0, stream>>>(bufB, feat, sdm);
    k_softmax4000<<<1, 256, 0, stream>>>(sdm, sdm);
    k_facts_part<<<40, 256, 0, stream>>>(bufB, sdm, wmed, part1, part2);
    k_hidden_part<<<48, 256, 0, stream>>>(feat, part1, part2, out_w1, hpart);
    k_result<<<125, 256, 0, stream>>>(hpart, out_b1, out_w2, out_b2, out, sp);
    k_bneg<<<VMED / 8, 256, 0, stream>>>(ddi_raw, sp, bpart);
    FastRx_wo_Diag_19473381720179_kernel<<<1, 256, 0, stream>>>(bpart, out);
}

// Round 11
// 431.081 us; speedup vs baseline: 1.4279x; 1.0585x over previous
//
#include <hip/hip_runtime.h>
#include <hip/hip_bf16.h>

#define NV 64
#define NP 32
#define NM 16
#define VMED 4000
#define EMB 256
#define EMBFF 128
#define CAP 128   // max cached nnz/row (mean ~41; verified exact in R10)

// NOTE (hard-won, rounds 0-7): ALL float inputs and the output are FP32.
// Misreading them as bf16 gives parity-dependent mantissa garbage.

__device__ __forceinline__ float block_sum_256(float v, float* red) {
    int t = threadIdx.x;
    red[t] = v; __syncthreads();
    for (int s = 128; s > 0; s >>= 1) { if (t < s) red[t] += red[t + s]; __syncthreads(); }
    float r = red[0]; __syncthreads();
    return r;
}
__device__ __forceinline__ float block_max_256(float v, float* red) {
    int t = threadIdx.x;
    red[t] = v; __syncthreads();
    for (int s = 128; s > 0; s >>= 1) { if (t < s) red[t] = fmaxf(red[t], red[t + s]); __syncthreads(); }
    float r = red[0]; __syncthreads();
    return r;
}

// K1: fused embed_conv + qkv. Block = one visit, 256 threads.
__global__ void k_ff1(const int* __restrict__ proc, const float* __restrict__ emb,
                      const float* __restrict__ cw, const float* __restrict__ cb,
                      const float* __restrict__ wq, const float* __restrict__ wk,
                      const float* __restrict__ wv, const float* __restrict__ alpha,
                      float* __restrict__ q, float* __restrict__ k, float* __restrict__ v,
                      float* __restrict__ qaw) {
    __shared__ float sm[EMBFF + 2];
    __shared__ float x[EMBFF];
    __shared__ float red[256];
    int vi = blockIdx.x, t = threadIdx.x;
    if (t < EMBFF) {
        float s = 0.f;
        for (int c = 0; c < NP; c++) s += emb[proc[vi * NP + c] * EMBFF + t];
        sm[t + 1] = s * (1.0f / NP);
    }
    if (t == 0) { sm[0] = 0.f; sm[EMBFF + 1] = 0.f; }
    __syncthreads();
    if (t < EMBFF) {
        float o = cw[0] * sm[t] + cw[1] * sm[t + 1] + cw[2] * sm[t + 2] + cb[0];
        x[t] = o > 0.f ? o : 0.f;
    }
    __syncthreads();
    float aq = 0, ak = 0, av = 0;
    for (int e = 0; e < EMBFF; e++) {
        float xe = x[e];
        aq += xe * wq[e * EMB + t];
        ak += xe * wk[e * EMB + t];
        av += xe * wv[e * EMB + t];
    }
    q[vi * EMB + t] = aq; k[vi * EMB + t] = ak; v[vi * EMB + t] = av;
    const float scale = 0.0625f;
    float z = aq * alpha[t] * scale;
    float m = block_max_256(z, red);
    float e_ = __expf(z - m);
    float sum = block_sum_256(e_, red);
    qaw[vi * EMB + t] = aq * (e_ / sum);
}

// K2: gq = colsum(qaw) inline; p = gq*k; pbw = p*softmax(p*beta*scale)
__global__ void k_pbw(const float* __restrict__ qaw, const float* __restrict__ k,
                      const float* __restrict__ beta, float* __restrict__ pbw) {
    __shared__ float red[256];
    int vi = blockIdx.x, f = threadIdx.x;
    float g = 0;
    for (int r = 0; r < NV; r++) g += qaw[r * EMB + f];
    float p = g * k[vi * EMB + f];
    const float scale = 0.0625f;
    float z = p * beta[f] * scale;
    float m = block_max_256(z, red);
    float e_ = __expf(z - m);
    float sum = block_sum_256(e_, red);
    pbw[vi * EMB + f] = p * (e_ / sum);
}

// K3: gk = colsum(pbw) inline; feat = (gk*v) @ wr + q
__global__ void k_feat(const float* __restrict__ pbw, const float* __restrict__ v,
                       const float* __restrict__ q, const float* __restrict__ wr,
                       float* __restrict__ feat) {
    __shared__ float s[EMB];
    int vi = blockIdx.x, f = threadIdx.x;
    float g = 0;
    for (int r = 0; r < NV; r++) g += pbw[r * EMB + f];
    s[f] = g * v[vi * EMB + f];
    __syncthreads();
    float acc = 0;
    for (int e = 0; e < EMB; e++) acc += s[e] * wr[e * EMB + f];
    feat[vi * EMB + f] = acc + q[vi * EMB + f];
}

// K4: visit_w = softmax(query @ hist.T); w_med = visit_w @ hv (SET dedup)
__global__ void k_visitw_wmed(const float* __restrict__ feat, const int* __restrict__ med,
                              float* __restrict__ w_med) {
    __shared__ float qs[EMB];
    __shared__ float vw[64];
    __shared__ float red[256];
    __shared__ float wm[VMED];
    int t = threadIdx.x;
    for (int e = t; e < EMB; e += 256) qs[e] = feat[63 * EMB + e];
    for (int i = t; i < VMED; i += 256) wm[i] = 0.f;
    __syncthreads();
    float sc = -1e30f;
    if (t < 63) {
        float a = 0;
        for (int e = 0; e < EMB; e++) a += qs[e] * feat[t * EMB + e];
        sc = a;
    }
    float m = block_max_256(sc, red);
    float e_ = (t < 63) ? __expf(sc - m) : 0.f;
    float sum = block_sum_256(e_, red);
    if (t < 63) vw[t] = e_ / sum;
    __syncthreads();
    for (int i = t; i < 63 * NM; i += 256) {
        int vv = i / NM, mm = i % NM;
        int code = med[vv * NM + mm];
        bool dup = false;
        for (int m2 = 0; m2 < mm; m2++)
            if (med[vv * NM + m2] == code) dup = true;
        if (!dup) atomicAdd(&wm[code], vw[vv]);  // LDS atomic
    }
    __syncthreads();
    for (int i = t; i < VMED; i += 256) w_med[i] = wm[i];
}

// K5: fused GCN front-half for BOTH graphs in one dispatch (1000 blocks):
// block b<500 handles ehr rows 8b..8b+7; b>=500 ddi rows. Per row: float4 scan
// -> CSR cache -> h=relu(adj@w1+b1) in LDS; then 8-row h@w2 -> out (h never
// touches DRAM).
__global__ void k_gcn(const float* __restrict__ eadj, const float* __restrict__ dadj,
                      const float* __restrict__ ew1, const float* __restrict__ eb1,
                      const float* __restrict__ ew2,
                      const float* __restrict__ dw1, const float* __restrict__ db1,
                      const float* __restrict__ dw2,
                      float* __restrict__ outE, float* __restrict__ outD,
                      int* __restrict__ ccntE, int* __restrict__ cidxE, float* __restrict__ cvalE,
                      int* __restrict__ ccntD, int* __restrict__ cidxD, float* __restrict__ cvalD) {
    __shared__ float x[8][EMB];
    __shared__ int idx[CAP];
    __shared__ float val[CAP];
    __shared__ int cnt;
    int b = blockIdx.x, t = threadIdx.x;
    bool isD = b >= 500;
    const float* adj = isD ? dadj : eadj;
    const float* w1  = isD ? dw1  : ew1;
    const float* b1  = isD ? db1  : eb1;
    const float* w2  = isD ? dw2  : ew2;
    float* outp = isD ? outD : outE;
    int*   ccnt = isD ? ccntD : ccntE;
    int*   cidx = isD ? cidxD : cidxE;
    float* cval = isD ? cvalD : cvalE;
    int r0 = (isD ? b - 500 : b) * 8;
    for (int r = 0; r < 8; r++) {
        int i = r0 + r;
        if (t == 0) cnt = 0;
        __syncthreads();
        const float4* row4 = (const float4*)(adj + (size_t)i * VMED);
        for (int j4 = t; j4 < VMED / 4; j4 += 256) {
            float4 a = row4[j4];
            if (a.x != 0.f) { int p = atomicAdd(&cnt, 1); if (p < CAP) { idx[p] = 4*j4+0; val[p] = a.x; } }
            if (a.y != 0.f) { int p = atomicAdd(&cnt, 1); if (p < CAP) { idx[p] = 4*j4+1; val[p] = a.y; } }
            if (a.z != 0.f) { int p = atomicAdd(&cnt, 1); if (p < CAP) { idx[p] = 4*j4+2; val[p] = a.z; } }
            if (a.w != 0.f) { int p = atomicAdd(&cnt, 1); if (p < CAP) { idx[p] = 4*j4+3; val[p] = a.w; } }
        }
        __syncthreads();
        int n = cnt < CAP ? cnt : CAP;
        if (t == 0) ccnt[i] = n;
        if (t < n) { cidx[i * CAP + t] = idx[t]; cval[i * CAP + t] = val[t]; }
        float acc = b1[t];
        for (int e = 0; e < n; e++) acc += val[e] * w1[idx[e] * EMB + t];
        x[r][t] = acc > 0.f ? acc : 0.f;
        __syncthreads();
    }
    float a[8] = {0, 0, 0, 0, 0, 0, 0, 0};
    #pragma unroll 4
    for (int e = 0; e < EMB; e++) {
        float we = w2[e * EMB + t];
        #pragma unroll
        for (int r = 0; r < 8; r++) a[r] += x[r][e] * we;
    }
    for (int r = 0; r < 8; r++) outp[(size_t)(r0 + r) * EMB + t] = a[r];
}

// K6: dm = (ehr_adj@xe + eb2) - inter*(ddi_adj@xd + db2), both via cached CSR.
__global__ void k_acc(const int* __restrict__ ccntE, const int* __restrict__ cidxE,
                      const float* __restrict__ cvalE,
                      const int* __restrict__ ccntD, const int* __restrict__ cidxD,
                      const float* __restrict__ cvalD,
                      const float* __restrict__ xe, const float* __restrict__ xd,
                      const float* __restrict__ b2e, const float* __restrict__ b2d,
                      const float* __restrict__ inter, float* __restrict__ dm) {
    __shared__ int idx[CAP];
    __shared__ float val[CAP];
    int i = blockIdx.x, t = threadIdx.x;
    int nE = ccntE[i];
    if (t < nE) { idx[t] = cidxE[i * CAP + t]; val[t] = cvalE[i * CAP + t]; }
    __syncthreads();
    float aE = b2e[t];
    for (int e = 0; e < nE; e++) aE += val[e] * xe[(size_t)idx[e] * EMB + t];
    __syncthreads();
    int nD = ccntD[i];
    if (t < nD) { idx[t] = cidxD[i * CAP + t]; val[t] = cvalD[i * CAP + t]; }
    __syncthreads();
    float aD = b2d[t];
    for (int e = 0; e < nD; e++) aD += val[e] * xd[(size_t)idx[e] * EMB + t];
    dm[(size_t)i * EMB + t] = aE - inter[0] * aD;
}

// K7: s_dm[i] = dot(query, dm[i])
__global__ void k_scores(const float* __restrict__ dm, const float* __restrict__ feat,
                         float* __restrict__ s_dm) {
    __shared__ float red[256];
    int i = blockIdx.x, t = threadIdx.x;
    float s = dm[(size_t)i * EMB + t] * feat[63 * EMB + t];
    s = block_sum_256(s, red);
    if (t == 0) s_dm[i] = s;
}

// K8: softmax over 4000 (in-place safe)
__global__ void k_softmax4000(const float* __restrict__ s, float* __restrict__ out) {
    __shared__ float red[256];
    int t = threadIdx.x;
    float m = -1e30f;
    for (int i = t; i < VMED; i += 256) m = fmaxf(m, s[i]);
    m = block_max_256(m, red);
    float sum = 0;
    for (int i = t; i < VMED; i += 256) { float e = __expf(s[i] - m); out[i] = e; sum += e; }
    sum = block_sum_256(sum, red);
    float inv = 1.f / sum;
    for (int i = t; i < VMED; i += 256) out[i] *= inv;
}

// K9: partials of fact1 = key_w1 @ dm, fact2 = w_med @ dm. 40 blocks x 100 rows.
__global__ void k_facts_part(const float* __restrict__ dm, const float* __restrict__ kw,
                             const float* __restrict__ wm, float* __restrict__ part1,
                             float* __restrict__ part2) {
    int f = threadIdx.x, b = blockIdx.x;
    int r0 = b * 100;
    float a1 = 0, a2 = 0;
    for (int r = r0; r < r0 + 100; r++) {
        float d = dm[(size_t)r * EMB + f];
        a1 += kw[r] * d;
        a2 += wm[r] * d;
    }
    part1[b * EMB + f] = a1;
    part2[b * EMB + f] = a2;
}

// K10: K-partitioned hidden matvec (48 blocks x 16 e-rows of out_w1)
__global__ void k_hidden_part(const float* __restrict__ feat, const float* __restrict__ part1,
                              const float* __restrict__ part2, const float* __restrict__ w1,
                              float* __restrict__ hpart) {
    __shared__ float xs[16];
    int b = blockIdx.x, t = threadIdx.x;
    int e0 = b * 16;
    if (t < 16) {
        int e = e0 + t;
        float xv;
        if (e < 256) xv = feat[63 * EMB + e];
        else if (e < 512) { float s = 0; for (int p = 0; p < 40; p++) s += part1[p * EMB + (e - 256)]; xv = s; }
        else              { float s = 0; for (int p = 0; p < 40; p++) s += part2[p * EMB + (e - 512)]; xv = s; }
        xs[t] = xv;
    }
    __syncthreads();
    float a1 = 0, a2 = 0;
    #pragma unroll
    for (int i = 0; i < 16; i++) {
        int e = e0 + i;
        a1 += xs[i] * w1[e * 512 + t];
        a2 += xs[i] * w1[e * 512 + t + 256];
    }
    hpart[b * 512 + t] = a1;
    hpart[b * 512 + t + 256] = a2;
}

// K11: hidden = relu(sum hpart + b1); result = hidden @ out_w2 + out_b2; sp = sigmoid.
__global__ void k_result(const float* __restrict__ hpart, const float* __restrict__ b1,
                         const float* __restrict__ w2, const float* __restrict__ b2,
                         float* __restrict__ out, float* __restrict__ sp) {
    __shared__ float hx[512];
    __shared__ float red[8][32];
    int t = threadIdx.x;
    for (int jj = t; jj < 512; jj += 256) {
        float s = b1[jj];
        for (int p = 0; p < 48; p++) s += hpart[p * 512 + jj];
        hx[jj] = s > 0.f ? s : 0.f;
    }
    __syncthreads();
    int lane = t & 31, seg = t >> 5;
    int j = blockIdx.x * 32 + lane;
    float acc = 0;
    int e0 = seg * 64;
    #pragma unroll 8
    for (int e = e0; e < e0 + 64; e++) acc += hx[e] * w2[(size_t)e * VMED + j];
    red[seg][lane] = acc;
    __syncthreads();
    if (seg == 0) {
        float s = b2[j];
        for (int p = 0; p < 8; p++) s += red[p][lane];
        out[j] = s;
        sp[j] = 1.f / (1.f + __expf(-s));
    }
}

// K12: bpart[i] = sp[i] * (ddi_raw[i,:] . sp) -- 8 rows/block, float4 + LDS sp
__global__ void k_bneg(const float* __restrict__ ddi, const float* __restrict__ sp,
                       float* __restrict__ bpart) {
    __shared__ float4 spl[VMED / 4];
    __shared__ float red[256];
    int t = threadIdx.x;
    const float4* sp4 = (const float4*)sp;
    for (int j4 = t; j4 < VMED / 4; j4 += 256) spl[j4] = sp4[j4];
    __syncthreads();
    for (int rr = 0; rr < 8; rr++) {
        int i = blockIdx.x * 8 + rr;
        const float4* row4 = (const float4*)(ddi + (size_t)i * VMED);
        float p = 0;
        for (int j4 = t; j4 < VMED / 4; j4 += 256) {
            float4 a = row4[j4];
            float4 s4 = spl[j4];
            p += a.x * s4.x + a.y * s4.y + a.z * s4.z + a.w * s4.w;
        }
        p = block_sum_256(p, red);
        if (t == 0) bpart[i] = sp[i] * p;
    }
}

// K13: batch_neg = 0.0005 * sum(bpart) -> out[4000]
__global__ void FastRx_wo_Diag_19473381720179_kernel(const float* __restrict__ bpart,
                                                     float* __restrict__ out) {
    __shared__ float red[256];
    int t = threadIdx.x;
    float s = 0;
    for (int i = t; i < VMED; i += 256) s += bpart[i];
    s = block_sum_256(s, red);
    if (t == 0) out[VMED] = 0.0005f * s;
}

extern "C" __attribute__((visibility("default")))
void kernel_launch(void* const* d_in, const int* in_sizes, int n_in,
                   void* d_out, int out_size, void* d_ws, size_t ws_size,
                   hipStream_t stream) {
    const int*   proc_codes = (const int*)d_in[0];
    const int*   med_codes  = (const int*)d_in[1];
    const float* emb_table  = (const float*)d_in[2];
    const float* conv_w     = (const float*)d_in[3];
    const float* conv_b     = (const float*)d_in[4];
    const float* wq         = (const float*)d_in[5];
    const float* wk         = (const float*)d_in[6];
    const float* wv         = (const float*)d_in[7];
    const float* wr         = (const float*)d_in[8];
    const float* alpha      = (const float*)d_in[9];
    const float* beta       = (const float*)d_in[10];
    const float* ehr_adj    = (const float*)d_in[11];
    const float* ddi_adj    = (const float*)d_in[12];
    const float* ddi_raw    = (const float*)d_in[13];
    const float* ehr_w1     = (const float*)d_in[14];
    const float* ehr_b1     = (const float*)d_in[15];
    const float* ehr_w2     = (const float*)d_in[16];
    const float* ehr_b2     = (const float*)d_in[17];
    const float* ddi_w1     = (const float*)d_in[18];
    const float* ddi_b1     = (const float*)d_in[19];
    const float* ddi_w2     = (const float*)d_in[20];
    const float* ddi_b2     = (const float*)d_in[21];
    const float* inter      = (const float*)d_in[22];
    const float* out_w1     = (const float*)d_in[23];
    const float* out_b1     = (const float*)d_in[24];
    const float* out_w2     = (const float*)d_in[25];
    const float* out_b2     = (const float*)d_in[26];
    float* out = (float*)d_out;   // fp32: result[4000] ++ batch_neg[1]

    float* w = (float*)d_ws;
    float* q      = w;                  // 16384
    float* k      = w + 16384;          // 16384
    float* v      = w + 32768;          // 16384
    float* tmpA   = w + 49152;          // 16384 (qaw)
    float* tmpB   = w + 65536;          // 16384 (pbw)
    float* feat   = w + 81920;          // 16384
    float* wmed   = w + 98304;          // 4096
    float* sdm    = w + 102400;         // 4096 (softmax in-place -> key_w1)
    float* sp     = w + 106496;         // 4096
    float* bufA   = w + 110592;         // 1,024,000 (t2 ehr)
    float* bufC   = bufA + 1024000;     // 1,024,000 (t2 ddi)
    float* bufB   = bufC + 1024000;     // 1,024,000 (dm)
    int*   ccntE  = (int*)(bufB + 1024000);   // 4096
    int*   cidxE  = ccntE + 4096;             // 512000
    float* cvalE  = (float*)(cidxE + 512000); // 512000
    int*   ccntD  = (int*)(cvalE + 512000);   // 4096
    int*   cidxD  = ccntD + 4096;             // 512000
    float* cvalD  = (float*)(cidxD + 512000); // 512000
    // aliases into dead bufA (first written AFTER last read of bufA in k_acc):
    float* part1  = bufA;               // 40*256
    float* part2  = bufA + 10240;       // 40*256
    float* hpart  = bufA + 20480;       // 48*512
    float* bpart  = bufA + 45056;       // 4096
    // total ws ~21 MB (ws_size = 256 MiB per poison profile)

    k_ff1<<<NV, EMB, 0, stream>>>(proc_codes, emb_table, conv_w, conv_b,
                                  wq, wk, wv, alpha, q, k, v, tmpA);
    k_pbw<<<NV, EMB, 0, stream>>>(tmpA, k, beta, tmpB);
    k_feat<<<NV, EMB, 0, stream>>>(tmpB, v, q, wr, feat);
    k_visitw_wmed<<<1, 256, 0, stream>>>(feat, med_codes, wmed);

    // Both GCN front halves in one dispatch; h stays in LDS.
    k_gcn<<<1000, 256, 0, stream>>>(ehr_adj, ddi_adj,
                                    ehr_w1, ehr_b1, ehr_w2,
                                    ddi_w1, ddi_b1, ddi_w2,
                                    bufA, bufC,
                                    ccntE, cidxE, cvalE, ccntD, cidxD, cvalD);
    // dm = ehr_gcn - inter * ddi_gcn, via cached CSRs.
    k_acc<<<VMED, 256, 0, stream>>>(ccntE, cidxE, cvalE, ccntD, cidxD, cvalD,
                                    bufA, bufC, ehr_b2, ddi_b2, inter, bufB);

    k_scores<<<VMED, 256, 0, stream>>>(bufB, feat, sdm);
    k_softmax4000<<<1, 256, 0, stream>>>(sdm, sdm);
    k_facts_part<<<40, 256, 0, stream>>>(bufB, sdm, wmed, part1, part2);
    k_hidden_part<<<48, 256, 0, stream>>>(feat, part1, part2, out_w1, hpart);
    k_result<<<125, 256, 0, stream>>>(hpart, out_b1, out_w2, out_b2, out, sp);
    k_bneg<<<VMED / 8, 256, 0, stream>>>(ddi_raw, sp, bpart);
    FastRx_wo_Diag_19473381720179_kernel<<<1, 256, 0, stream>>>(bpart, out);
}

// Round 12
// 426.896 us; speedup vs baseline: 1.4419x; 1.0098x over previous
//
#include <hip/hip_runtime.h>
#include <hip/hip_bf16.h>

#define NV 64
#define NP 32
#define NM 16
#define VMED 4000
#define EMB 256
#define EMBFF 128
#define CAP 128   // max cached nnz/row (mean ~41; verified in R10)

// NOTE (hard-won, rounds 0-7): ALL float inputs and the output are FP32.
// Misreading them as bf16 gives parity-dependent mantissa garbage.

__device__ __forceinline__ float block_sum_256(float v, float* red) {
    int t = threadIdx.x;
    red[t] = v; __syncthreads();
    for (int s = 128; s > 0; s >>= 1) { if (t < s) red[t] += red[t + s]; __syncthreads(); }
    float r = red[0]; __syncthreads();
    return r;
}
__device__ __forceinline__ float block_max_256(float v, float* red) {
    int t = threadIdx.x;
    red[t] = v; __syncthreads();
    for (int s = 128; s > 0; s >>= 1) { if (t < s) red[t] = fmaxf(red[t], red[t + s]); __syncthreads(); }
    float r = red[0]; __syncthreads();
    return r;
}

// K1: fused embed_conv + qkv. Block = one visit, 256 threads.
__global__ void k_ff1(const int* __restrict__ proc, const float* __restrict__ emb,
                      const float* __restrict__ cw, const float* __restrict__ cb,
                      const float* __restrict__ wq, const float* __restrict__ wk,
                      const float* __restrict__ wv, const float* __restrict__ alpha,
                      float* __restrict__ q, float* __restrict__ k, float* __restrict__ v,
                      float* __restrict__ qaw) {
    __shared__ float sm[EMBFF + 2];
    __shared__ float x[EMBFF];
    __shared__ float red[256];
    int vi = blockIdx.x, t = threadIdx.x;
    if (t < EMBFF) {
        float s = 0.f;
        for (int c = 0; c < NP; c++) s += emb[proc[vi * NP + c] * EMBFF + t];
        sm[t + 1] = s * (1.0f / NP);
    }
    if (t == 0) { sm[0] = 0.f; sm[EMBFF + 1] = 0.f; }
    __syncthreads();
    if (t < EMBFF) {
        float o = cw[0] * sm[t] + cw[1] * sm[t + 1] + cw[2] * sm[t + 2] + cb[0];
        x[t] = o > 0.f ? o : 0.f;
    }
    __syncthreads();
    float aq = 0, ak = 0, av = 0;
    for (int e = 0; e < EMBFF; e++) {
        float xe = x[e];
        aq += xe * wq[e * EMB + t];
        ak += xe * wk[e * EMB + t];
        av += xe * wv[e * EMB + t];
    }
    q[vi * EMB + t] = aq; k[vi * EMB + t] = ak; v[vi * EMB + t] = av;
    const float scale = 0.0625f;
    float z = aq * alpha[t] * scale;
    float m = block_max_256(z, red);
    float e_ = __expf(z - m);
    float sum = block_sum_256(e_, red);
    qaw[vi * EMB + t] = aq * (e_ / sum);
}

// K2: gq = colsum(qaw) inline; p = gq*k; pbw = p*softmax(p*beta*scale)
__global__ void k_pbw(const float* __restrict__ qaw, const float* __restrict__ k,
                      const float* __restrict__ beta, float* __restrict__ pbw) {
    __shared__ float red[256];
    int vi = blockIdx.x, f = threadIdx.x;
    float g = 0;
    for (int r = 0; r < NV; r++) g += qaw[r * EMB + f];
    float p = g * k[vi * EMB + f];
    const float scale = 0.0625f;
    float z = p * beta[f] * scale;
    float m = block_max_256(z, red);
    float e_ = __expf(z - m);
    float sum = block_sum_256(e_, red);
    pbw[vi * EMB + f] = p * (e_ / sum);
}

// K3: gk = colsum(pbw) inline; feat = (gk*v) @ wr + q
__global__ void k_feat(const float* __restrict__ pbw, const float* __restrict__ v,
                       const float* __restrict__ q, const float* __restrict__ wr,
                       float* __restrict__ feat) {
    __shared__ float s[EMB];
    int vi = blockIdx.x, f = threadIdx.x;
    float g = 0;
    for (int r = 0; r < NV; r++) g += pbw[r * EMB + f];
    s[f] = g * v[vi * EMB + f];
    __syncthreads();
    float acc = 0;
    for (int e = 0; e < EMB; e++) acc += s[e] * wr[e * EMB + f];
    feat[vi * EMB + f] = acc + q[vi * EMB + f];
}

// K4: visit_w = softmax(query @ hist.T); w_med = visit_w @ hv (SET dedup)
__global__ void k_visitw_wmed(const float* __restrict__ feat, const int* __restrict__ med,
                              float* __restrict__ w_med) {
    __shared__ float qs[EMB];
    __shared__ float vw[64];
    __shared__ float red[256];
    __shared__ float wm[VMED];
    int t = threadIdx.x;
    for (int e = t; e < EMB; e += 256) qs[e] = feat[63 * EMB + e];
    for (int i = t; i < VMED; i += 256) wm[i] = 0.f;
    __syncthreads();
    float sc = -1e30f;
    if (t < 63) {
        float a = 0;
        for (int e = 0; e < EMB; e++) a += qs[e] * feat[t * EMB + e];
        sc = a;
    }
    float m = block_max_256(sc, red);
    float e_ = (t < 63) ? __expf(sc - m) : 0.f;
    float sum = block_sum_256(e_, red);
    if (t < 63) vw[t] = e_ / sum;
    __syncthreads();
    for (int i = t; i < 63 * NM; i += 256) {
        int vv = i / NM, mm = i % NM;
        int code = med[vv * NM + mm];
        bool dup = false;
        for (int m2 = 0; m2 < mm; m2++)
            if (med[vv * NM + m2] == code) dup = true;
        if (!dup) atomicAdd(&wm[code], vw[vv]);  // LDS atomic
    }
    __syncthreads();
    for (int i = t; i < VMED; i += 256) w_med[i] = wm[i];
}

// K5: fused GCN front-half, BOTH graphs, 1000 blocks. Per block: ONE barrier-free
// coalesced float4 scan of 8 contiguous rows (per-row LDS CSR buffers), then
// h = relu(adj@w1+b1) for the 8 rows (no barriers), then 8-row h@w2.
__global__ void k_gcn(const float* __restrict__ eadj, const float* __restrict__ dadj,
                      const float* __restrict__ ew1, const float* __restrict__ eb1,
                      const float* __restrict__ ew2,
                      const float* __restrict__ dw1, const float* __restrict__ db1,
                      const float* __restrict__ dw2,
                      float* __restrict__ outE, float* __restrict__ outD,
                      int* __restrict__ ccntE, int* __restrict__ cidxE, float* __restrict__ cvalE,
                      int* __restrict__ ccntD, int* __restrict__ cidxD, float* __restrict__ cvalD) {
    __shared__ float x[8][EMB];
    __shared__ int idx[8][CAP];
    __shared__ float val[8][CAP];
    __shared__ int cnt[8];
    int b = blockIdx.x, t = threadIdx.x;
    bool isD = b >= 500;
    const float* adj = isD ? dadj : eadj;
    const float* w1  = isD ? dw1  : ew1;
    const float* b1  = isD ? db1  : eb1;
    const float* w2  = isD ? dw2  : ew2;
    float* outp = isD ? outD : outE;
    int*   ccnt = isD ? ccntD : ccntE;
    int*   cidx = isD ? cidxD : cidxE;
    float* cval = isD ? cvalD : cvalE;
    int r0 = (isD ? b - 500 : b) * 8;
    if (t < 8) cnt[t] = 0;
    __syncthreads();
    // one coalesced pass over 8*4000 floats (128 KB contiguous)
    const float4* base4 = (const float4*)(adj + (size_t)r0 * VMED);
    const int Q = VMED / 4;  // 1000 float4 per row
    for (int jj = t; jj < 8 * Q; jj += 256) {
        float4 a = base4[jj];
        int r = jj / Q;                  // compiler magic-mul
        int c0 = (jj - r * Q) * 4;
        if (a.x != 0.f) { int p = atomicAdd(&cnt[r], 1); if (p < CAP) { idx[r][p] = c0;     val[r][p] = a.x; } }
        if (a.y != 0.f) { int p = atomicAdd(&cnt[r], 1); if (p < CAP) { idx[r][p] = c0 + 1; val[r][p] = a.y; } }
        if (a.z != 0.f) { int p = atomicAdd(&cnt[r], 1); if (p < CAP) { idx[r][p] = c0 + 2; val[r][p] = a.z; } }
        if (a.w != 0.f) { int p = atomicAdd(&cnt[r], 1); if (p < CAP) { idx[r][p] = c0 + 3; val[r][p] = a.w; } }
    }
    __syncthreads();
    // CSR writeback + h rows (no inter-row barriers; all deps settled above)
    for (int r = 0; r < 8; r++) {
        int n = cnt[r] < CAP ? cnt[r] : CAP;
        if (t == 0) ccnt[r0 + r] = n;
        if (t < n) { cidx[(r0 + r) * CAP + t] = idx[r][t]; cval[(r0 + r) * CAP + t] = val[r][t]; }
        float acc = b1[t];
        for (int e = 0; e < n; e++) acc += val[r][e] * w1[idx[r][e] * EMB + t];
        x[r][t] = acc > 0.f ? acc : 0.f;
    }
    __syncthreads();
    float a[8] = {0, 0, 0, 0, 0, 0, 0, 0};
    #pragma unroll 4
    for (int e = 0; e < EMB; e++) {
        float we = w2[e * EMB + t];
        #pragma unroll
        for (int r = 0; r < 8; r++) a[r] += x[r][e] * we;
    }
    for (int r = 0; r < 8; r++) outp[(size_t)(r0 + r) * EMB + t] = a[r];
}

// K6: dm = (ehr@xe + eb2) - inter*(ddi@xd + db2) via cached CSRs;
//     fused: sdm[i] = dot(query, dm[i]).
__global__ void k_acc(const int* __restrict__ ccntE, const int* __restrict__ cidxE,
                      const float* __restrict__ cvalE,
                      const int* __restrict__ ccntD, const int* __restrict__ cidxD,
                      const float* __restrict__ cvalD,
                      const float* __restrict__ xe, const float* __restrict__ xd,
                      const float* __restrict__ b2e, const float* __restrict__ b2d,
                      const float* __restrict__ inter, const float* __restrict__ feat,
                      float* __restrict__ dm, float* __restrict__ sdm) {
    __shared__ int idx[CAP];
    __shared__ float val[CAP];
    __shared__ float red[256];
    int i = blockIdx.x, t = threadIdx.x;
    int nE = ccntE[i];
    if (t < nE) { idx[t] = cidxE[i * CAP + t]; val[t] = cvalE[i * CAP + t]; }
    __syncthreads();
    float aE = b2e[t];
    for (int e = 0; e < nE; e++) aE += val[e] * xe[(size_t)idx[e] * EMB + t];
    __syncthreads();
    int nD = ccntD[i];
    if (t < nD) { idx[t] = cidxD[i * CAP + t]; val[t] = cvalD[i * CAP + t]; }
    __syncthreads();
    float aD = b2d[t];
    for (int e = 0; e < nD; e++) aD += val[e] * xd[(size_t)idx[e] * EMB + t];
    float dmv = aE - inter[0] * aD;
    dm[(size_t)i * EMB + t] = dmv;
    float s = block_sum_256(dmv * feat[63 * EMB + t], red);
    if (t == 0) sdm[i] = s;
}

// K7: softmax over 4000 (in-place safe)
__global__ void k_softmax4000(const float* __restrict__ s, float* __restrict__ out) {
    __shared__ float red[256];
    int t = threadIdx.x;
    float m = -1e30f;
    for (int i = t; i < VMED; i += 256) m = fmaxf(m, s[i]);
    m = block_max_256(m, red);
    float sum = 0;
    for (int i = t; i < VMED; i += 256) { float e = __expf(s[i] - m); out[i] = e; sum += e; }
    sum = block_sum_256(sum, red);
    float inv = 1.f / sum;
    for (int i = t; i < VMED; i += 256) out[i] *= inv;
}

// K8: partials of fact1 = key_w1 @ dm, fact2 = w_med @ dm. 40 blocks x 100 rows.
__global__ void k_facts_part(const float* __restrict__ dm, const float* __restrict__ kw,
                             const float* __restrict__ wm, float* __restrict__ part1,
                             float* __restrict__ part2) {
    int f = threadIdx.x, b = blockIdx.x;
    int r0 = b * 100;
    float a1 = 0, a2 = 0;
    for (int r = r0; r < r0 + 100; r++) {
        float d = dm[(size_t)r * EMB + f];
        a1 += kw[r] * d;
        a2 += wm[r] * d;
    }
    part1[b * EMB + f] = a1;
    part2[b * EMB + f] = a2;
}

// K9: K-partitioned hidden matvec (48 blocks x 16 e-rows of out_w1)
__global__ void k_hidden_part(const float* __restrict__ feat, const float* __restrict__ part1,
                              const float* __restrict__ part2, const float* __restrict__ w1,
                              float* __restrict__ hpart) {
    __shared__ float xs[16];
    int b = blockIdx.x, t = threadIdx.x;
    int e0 = b * 16;
    if (t < 16) {
        int e = e0 + t;
        float xv;
        if (e < 256) xv = feat[63 * EMB + e];
        else if (e < 512) { float s = 0; for (int p = 0; p < 40; p++) s += part1[p * EMB + (e - 256)]; xv = s; }
        else              { float s = 0; for (int p = 0; p < 40; p++) s += part2[p * EMB + (e - 512)]; xv = s; }
        xs[t] = xv;
    }
    __syncthreads();
    float a1 = 0, a2 = 0;
    #pragma unroll
    for (int i = 0; i < 16; i++) {
        int e = e0 + i;
        a1 += xs[i] * w1[e * 512 + t];
        a2 += xs[i] * w1[e * 512 + t + 256];
    }
    hpart[b * 512 + t] = a1;
    hpart[b * 512 + t + 256] = a2;
}

// K10: hidden = relu(sum hpart + b1); result = hidden @ out_w2 + out_b2; sp = sigmoid.
__global__ void k_result(const float* __restrict__ hpart, const float* __restrict__ b1,
                         const float* __restrict__ w2, const float* __restrict__ b2,
                         float* __restrict__ out, float* __restrict__ sp) {
    __shared__ float hx[512];
    __shared__ float red[8][32];
    int t = threadIdx.x;
    for (int jj = t; jj < 512; jj += 256) {
        float s = b1[jj];
        for (int p = 0; p < 48; p++) s += hpart[p * 512 + jj];
        hx[jj] = s > 0.f ? s : 0.f;
    }
    __syncthreads();
    int lane = t & 31, seg = t >> 5;
    int j = blockIdx.x * 32 + lane;
    float acc = 0;
    int e0 = seg * 64;
    #pragma unroll 8
    for (int e = e0; e < e0 + 64; e++) acc += hx[e] * w2[(size_t)e * VMED + j];
    red[seg][lane] = acc;
    __syncthreads();
    if (seg == 0) {
        float s = b2[j];
        for (int p = 0; p < 8; p++) s += red[p][lane];
        out[j] = s;
        sp[j] = 1.f / (1.f + __expf(-s));
    }
}

// K11: bpart[i] = sp[i] * (ddi_raw[i,:] . sp) -- 8 rows/block, float4 + LDS sp
__global__ void k_bneg(const float* __restrict__ ddi, const float* __restrict__ sp,
                       float* __restrict__ bpart) {
    __shared__ float4 spl[VMED / 4];
    __shared__ float red[256];
    int t = threadIdx.x;
    const float4* sp4 = (const float4*)sp;
    for (int j4 = t; j4 < VMED / 4; j4 += 256) spl[j4] = sp4[j4];
    __syncthreads();
    for (int rr = 0; rr < 8; rr++) {
        int i = blockIdx.x * 8 + rr;
        const float4* row4 = (const float4*)(ddi + (size_t)i * VMED);
        float p = 0;
        for (int j4 = t; j4 < VMED / 4; j4 += 256) {
            float4 a = row4[j4];
            float4 s4 = spl[j4];
            p += a.x * s4.x + a.y * s4.y + a.z * s4.z + a.w * s4.w;
        }
        p = block_sum_256(p, red);
        if (t == 0) bpart[i] = sp[i] * p;
    }
}

// K12: batch_neg = 0.0005 * sum(bpart) -> out[4000]
__global__ void FastRx_wo_Diag_19473381720179_kernel(const float* __restrict__ bpart,
                                                     float* __restrict__ out) {
    __shared__ float red[256];
    int t = threadIdx.x;
    float s = 0;
    for (int i = t; i < VMED; i += 256) s += bpart[i];
    s = block_sum_256(s, red);
    if (t == 0) out[VMED] = 0.0005f * s;
}

extern "C" __attribute__((visibility("default")))
void kernel_launch(void* const* d_in, const int* in_sizes, int n_in,
                   void* d_out, int out_size, void* d_ws, size_t ws_size,
                   hipStream_t stream) {
    const int*   proc_codes = (const int*)d_in[0];
    const int*   med_codes  = (const int*)d_in[1];
    const float* emb_table  = (const float*)d_in[2];
    const float* conv_w     = (const float*)d_in[3];
    const float* conv_b     = (const float*)d_in[4];
    const float* wq         = (const float*)d_in[5];
    const float* wk         = (const float*)d_in[6];
    const float* wv         = (const float*)d_in[7];
    const float* wr         = (const float*)d_in[8];
    const float* alpha      = (const float*)d_in[9];
    const float* beta       = (const float*)d_in[10];
    const float* ehr_adj    = (const float*)d_in[11];
    const float* ddi_adj    = (const float*)d_in[12];
    const float* ddi_raw    = (const float*)d_in[13];
    const float* ehr_w1     = (const float*)d_in[14];
    const float* ehr_b1     = (const float*)d_in[15];
    const float* ehr_w2     = (const float*)d_in[16];
    const float* ehr_b2     = (const float*)d_in[17];
    const float* ddi_w1     = (const float*)d_in[18];
    const float* ddi_b1     = (const float*)d_in[19];
    const float* ddi_w2     = (const float*)d_in[20];
    const float* ddi_b2     = (const float*)d_in[21];
    const float* inter      = (const float*)d_in[22];
    const float* out_w1     = (const float*)d_in[23];
    const float* out_b1     = (const float*)d_in[24];
    const float* out_w2     = (const float*)d_in[25];
    const float* out_b2     = (const float*)d_in[26];
    float* out = (float*)d_out;   // fp32: result[4000] ++ batch_neg[1]

    float* w = (float*)d_ws;
    float* q      = w;                  // 16384
    float* k      = w + 16384;          // 16384
    float* v      = w + 32768;          // 16384
    float* tmpA   = w + 49152;          // 16384 (qaw)
    float* tmpB   = w + 65536;          // 16384 (pbw)
    float* feat   = w + 81920;          // 16384
    float* wmed   = w + 98304;          // 4096
    float* sdm    = w + 102400;         // 4096 (softmax in-place -> key_w1)
    float* sp     = w + 106496;         // 4096
    float* bufA   = w + 110592;         // 1,024,000 (t2 ehr)
    float* bufC   = bufA + 1024000;     // 1,024,000 (t2 ddi)
    float* bufB   = bufC + 1024000;     // 1,024,000 (dm)
    int*   ccntE  = (int*)(bufB + 1024000);   // 4096
    int*   cidxE  = ccntE + 4096;             // 512000
    float* cvalE  = (float*)(cidxE + 512000); // 512000
    int*   ccntD  = (int*)(cvalE + 512000);   // 4096
    int*   cidxD  = ccntD + 4096;             // 512000
    float* cvalD  = (float*)(cidxD + 512000); // 512000
    // aliases into dead bufA (first written AFTER last read of bufA in k_acc):
    float* part1  = bufA;               // 40*256
    float* part2  = bufA + 10240;       // 40*256
    float* hpart  = bufA + 20480;       // 48*512
    float* bpart  = bufA + 45056;       // 4096

    k_ff1<<<NV, EMB, 0, stream>>>(proc_codes, emb_table, conv_w, conv_b,
                                  wq, wk, wv, alpha, q, k, v, tmpA);
    k_pbw<<<NV, EMB, 0, stream>>>(tmpA, k, beta, tmpB);
    k_feat<<<NV, EMB, 0, stream>>>(tmpB, v, q, wr, feat);
    k_visitw_wmed<<<1, 256, 0, stream>>>(feat, med_codes, wmed);

    k_gcn<<<1000, 256, 0, stream>>>(ehr_adj, ddi_adj,
                                    ehr_w1, ehr_b1, ehr_w2,
                                    ddi_w1, ddi_b1, ddi_w2,
                                    bufA, bufC,
                                    ccntE, cidxE, cvalE, ccntD, cidxD, cvalD);
    k_acc<<<VMED, 256, 0, stream>>>(ccntE, cidxE, cvalE, ccntD, cidxD, cvalD,
                                    bufA, bufC, ehr_b2, ddi_b2, inter, feat,
                                    bufB, sdm);

    k_softmax4000<<<1, 256, 0, stream>>>(sdm, sdm);
    k_facts_part<<<40, 256, 0, stream>>>(bufB, sdm, wmed, part1, part2);
    k_hidden_part<<<48, 256, 0, stream>>>(feat, part1, part2, out_w1, hpart);
    k_result<<<125, 256, 0, stream>>>(hpart, out_b1, out_w2, out_b2, out, sp);
    k_bneg<<<VMED / 8, 256, 0, stream>>>(ddi_raw, sp, bpart);
    FastRx_wo_Diag_19473381720179_kernel<<<1, 256, 0, stream>>>(bpart, out);
}

// Round 13
// 424.761 us; speedup vs baseline: 1.4491x; 1.0050x over previous
//
#include <hip/hip_runtime.h>
#include <hip/hip_bf16.h>

#define NV 64
#define NP 32
#define NM 16
#define VMED 4000
#define EMB 256
#define EMBFF 128
#define CAP 128   // max cached nnz/row (mean ~41; verified in R10)

// NOTE (hard-won, rounds 0-7): ALL float inputs and the output are FP32.
// Misreading them as bf16 gives parity-dependent mantissa garbage.

__device__ __forceinline__ float block_sum_256(float v, float* red) {
    int t = threadIdx.x;
    red[t] = v; __syncthreads();
    for (int s = 128; s > 0; s >>= 1) { if (t < s) red[t] += red[t + s]; __syncthreads(); }
    float r = red[0]; __syncthreads();
    return r;
}
__device__ __forceinline__ float block_max_256(float v, float* red) {
    int t = threadIdx.x;
    red[t] = v; __syncthreads();
    for (int s = 128; s > 0; s >>= 1) { if (t < s) red[t] = fmaxf(red[t], red[t + s]); __syncthreads(); }
    float r = red[0]; __syncthreads();
    return r;
}

// K1: fused embed_conv + qkv. Block = one visit, 256 threads.
__global__ void k_ff1(const int* __restrict__ proc, const float* __restrict__ emb,
                      const float* __restrict__ cw, const float* __restrict__ cb,
                      const float* __restrict__ wq, const float* __restrict__ wk,
                      const float* __restrict__ wv, const float* __restrict__ alpha,
                      float* __restrict__ q, float* __restrict__ k, float* __restrict__ v,
                      float* __restrict__ qaw) {
    __shared__ float sm[EMBFF + 2];
    __shared__ float x[EMBFF];
    __shared__ float red[256];
    int vi = blockIdx.x, t = threadIdx.x;
    if (t < EMBFF) {
        float s = 0.f;
        for (int c = 0; c < NP; c++) s += emb[proc[vi * NP + c] * EMBFF + t];
        sm[t + 1] = s * (1.0f / NP);
    }
    if (t == 0) { sm[0] = 0.f; sm[EMBFF + 1] = 0.f; }
    __syncthreads();
    if (t < EMBFF) {
        float o = cw[0] * sm[t] + cw[1] * sm[t + 1] + cw[2] * sm[t + 2] + cb[0];
        x[t] = o > 0.f ? o : 0.f;
    }
    __syncthreads();
    float aq = 0, ak = 0, av = 0;
    for (int e = 0; e < EMBFF; e++) {
        float xe = x[e];
        aq += xe * wq[e * EMB + t];
        ak += xe * wk[e * EMB + t];
        av += xe * wv[e * EMB + t];
    }
    q[vi * EMB + t] = aq; k[vi * EMB + t] = ak; v[vi * EMB + t] = av;
    const float scale = 0.0625f;
    float z = aq * alpha[t] * scale;
    float m = block_max_256(z, red);
    float e_ = __expf(z - m);
    float sum = block_sum_256(e_, red);
    qaw[vi * EMB + t] = aq * (e_ / sum);
}

// K2: gq = colsum(qaw) inline; p = gq*k; pbw = p*softmax(p*beta*scale)
__global__ void k_pbw(const float* __restrict__ qaw, const float* __restrict__ k,
                      const float* __restrict__ beta, float* __restrict__ pbw) {
    __shared__ float red[256];
    int vi = blockIdx.x, f = threadIdx.x;
    float g = 0;
    for (int r = 0; r < NV; r++) g += qaw[r * EMB + f];
    float p = g * k[vi * EMB + f];
    const float scale = 0.0625f;
    float z = p * beta[f] * scale;
    float m = block_max_256(z, red);
    float e_ = __expf(z - m);
    float sum = block_sum_256(e_, red);
    pbw[vi * EMB + f] = p * (e_ / sum);
}

// K3: gk = colsum(pbw) inline; feat = (gk*v) @ wr + q
__global__ void k_feat(const float* __restrict__ pbw, const float* __restrict__ v,
                       const float* __restrict__ q, const float* __restrict__ wr,
                       float* __restrict__ feat) {
    __shared__ float s[EMB];
    int vi = blockIdx.x, f = threadIdx.x;
    float g = 0;
    for (int r = 0; r < NV; r++) g += pbw[r * EMB + f];
    s[f] = g * v[vi * EMB + f];
    __syncthreads();
    float acc = 0;
    for (int e = 0; e < EMB; e++) acc += s[e] * wr[e * EMB + f];
    feat[vi * EMB + f] = acc + q[vi * EMB + f];
}

// K4: visit_w = softmax(query @ hist.T); w_med = visit_w @ hv (SET dedup)
__global__ void k_visitw_wmed(const float* __restrict__ feat, const int* __restrict__ med,
                              float* __restrict__ w_med) {
    __shared__ float qs[EMB];
    __shared__ float vw[64];
    __shared__ float red[256];
    __shared__ float wm[VMED];
    int t = threadIdx.x;
    for (int e = t; e < EMB; e += 256) qs[e] = feat[63 * EMB + e];
    for (int i = t; i < VMED; i += 256) wm[i] = 0.f;
    __syncthreads();
    float sc = -1e30f;
    if (t < 63) {
        float a = 0;
        for (int e = 0; e < EMB; e++) a += qs[e] * feat[t * EMB + e];
        sc = a;
    }
    float m = block_max_256(sc, red);
    float e_ = (t < 63) ? __expf(sc - m) : 0.f;
    float sum = block_sum_256(e_, red);
    if (t < 63) vw[t] = e_ / sum;
    __syncthreads();
    for (int i = t; i < 63 * NM; i += 256) {
        int vv = i / NM, mm = i % NM;
        int code = med[vv * NM + mm];
        bool dup = false;
        for (int m2 = 0; m2 < mm; m2++)
            if (med[vv * NM + m2] == code) dup = true;
        if (!dup) atomicAdd(&wm[code], vw[vv]);  // LDS atomic
    }
    __syncthreads();
    for (int i = t; i < VMED; i += 256) w_med[i] = wm[i];
}

// K5: fused GCN front-half, BOTH graphs, 1000 blocks.
// Scan: 4-deep register-pipelined float4 stream (keeps >=4 loads in flight).
// Gather: unroll-by-4 with hoisted loads. Then 8-row h@w2.
__global__ void k_gcn(const float* __restrict__ eadj, const float* __restrict__ dadj,
                      const float* __restrict__ ew1, const float* __restrict__ eb1,
                      const float* __restrict__ ew2,
                      const float* __restrict__ dw1, const float* __restrict__ db1,
                      const float* __restrict__ dw2,
                      float* __restrict__ outE, float* __restrict__ outD,
                      int* __restrict__ ccntE, int* __restrict__ cidxE, float* __restrict__ cvalE,
                      int* __restrict__ ccntD, int* __restrict__ cidxD, float* __restrict__ cvalD) {
    __shared__ float x[8][EMB];
    __shared__ int idx[8][CAP];
    __shared__ float val[8][CAP];
    __shared__ int cnt[8];
    int b = blockIdx.x, t = threadIdx.x;
    bool isD = b >= 500;
    const float* adj = isD ? dadj : eadj;
    const float* w1  = isD ? dw1  : ew1;
    const float* b1  = isD ? db1  : eb1;
    const float* w2  = isD ? dw2  : ew2;
    float* outp = isD ? outD : outE;
    int*   ccnt = isD ? ccntD : ccntE;
    int*   cidx = isD ? cidxD : cidxE;
    float* cval = isD ? cvalD : cvalE;
    int r0 = (isD ? b - 500 : b) * 8;
    if (t < 8) cnt[t] = 0;
    __syncthreads();

    const float4* base4 = (const float4*)(adj + (size_t)r0 * VMED);
    const int Q = VMED / 4;      // 1000 float4 per row
    const int TOT = 8 * Q;       // 8000
    // 4-deep pipelined scan
    for (int j0 = t; j0 < TOT; j0 += 1024) {
        int j1 = j0 + 256, j2 = j0 + 512, j3 = j0 + 768;
        float4 a0 = base4[j0];
        float4 a1, a2, a3;
        bool v1 = j1 < TOT, v2 = j2 < TOT, v3 = j3 < TOT;
        if (v1) a1 = base4[j1];
        if (v2) a2 = base4[j2];
        if (v3) a3 = base4[j3];
        #define PROC(JJ, A)                                                         \
        {                                                                           \
            int r = (JJ) / Q;                                                       \
            int c0 = ((JJ) - r * Q) * 4;                                            \
            int c = (A.x != 0.f) + (A.y != 0.f) + (A.z != 0.f) + (A.w != 0.f);      \
            if (c) {                                                                \
                int p = atomicAdd(&cnt[r], c);                                      \
                if (A.x != 0.f) { if (p < CAP) { idx[r][p] = c0;     val[r][p] = A.x; } p++; } \
                if (A.y != 0.f) { if (p < CAP) { idx[r][p] = c0 + 1; val[r][p] = A.y; } p++; } \
                if (A.z != 0.f) { if (p < CAP) { idx[r][p] = c0 + 2; val[r][p] = A.z; } p++; } \
                if (A.w != 0.f) { if (p < CAP) { idx[r][p] = c0 + 3; val[r][p] = A.w; } p++; } \
            }                                                                       \
        }
        PROC(j0, a0);
        if (v1) PROC(j1, a1);
        if (v2) PROC(j2, a2);
        if (v3) PROC(j3, a3);
        #undef PROC
    }
    __syncthreads();

    // CSR writeback + h rows; gather unrolled by 4 (loads hoisted -> 4 in flight)
    for (int r = 0; r < 8; r++) {
        int n = cnt[r] < CAP ? cnt[r] : CAP;
        if (t == 0) ccnt[r0 + r] = n;
        if (t < n) { cidx[(r0 + r) * CAP + t] = idx[r][t]; cval[(r0 + r) * CAP + t] = val[r][t]; }
        float acc = b1[t];
        int e = 0;
        for (; e + 4 <= n; e += 4) {
            int i0 = idx[r][e], i1 = idx[r][e + 1], i2 = idx[r][e + 2], i3 = idx[r][e + 3];
            float g0 = w1[(size_t)i0 * EMB + t];
            float g1 = w1[(size_t)i1 * EMB + t];
            float g2 = w1[(size_t)i2 * EMB + t];
            float g3 = w1[(size_t)i3 * EMB + t];
            acc += val[r][e] * g0 + val[r][e + 1] * g1 + val[r][e + 2] * g2 + val[r][e + 3] * g3;
        }
        for (; e < n; e++) acc += val[r][e] * w1[(size_t)idx[r][e] * EMB + t];
        x[r][t] = acc > 0.f ? acc : 0.f;
    }
    __syncthreads();

    float a[8] = {0, 0, 0, 0, 0, 0, 0, 0};
    #pragma unroll 4
    for (int e = 0; e < EMB; e++) {
        float we = w2[e * EMB + t];
        #pragma unroll
        for (int r = 0; r < 8; r++) a[r] += x[r][e] * we;
    }
    for (int r = 0; r < 8; r++) outp[(size_t)(r0 + r) * EMB + t] = a[r];
}

// K6: dm = (ehr@xe + eb2) - inter*(ddi@xd + db2) via cached CSRs (separate LDS
// buffers, one barrier, unroll-4 gathers); fused sdm[i] = dot(query, dm[i]).
__global__ void k_acc(const int* __restrict__ ccntE, const int* __restrict__ cidxE,
                      const float* __restrict__ cvalE,
                      const int* __restrict__ ccntD, const int* __restrict__ cidxD,
                      const float* __restrict__ cvalD,
                      const float* __restrict__ xe, const float* __restrict__ xd,
                      const float* __restrict__ b2e, const float* __restrict__ b2d,
                      const float* __restrict__ inter, const float* __restrict__ feat,
                      float* __restrict__ dm, float* __restrict__ sdm) {
    __shared__ int idxE[CAP];
    __shared__ float valE[CAP];
    __shared__ int idxD[CAP];
    __shared__ float valD[CAP];
    __shared__ float red[256];
    int i = blockIdx.x, t = threadIdx.x;
    int nE = ccntE[i], nD = ccntD[i];
    if (t < nE) { idxE[t] = cidxE[i * CAP + t]; valE[t] = cvalE[i * CAP + t]; }
    if (t < nD) { idxD[t] = cidxD[i * CAP + t]; valD[t] = cvalD[i * CAP + t]; }
    __syncthreads();
    float aE = b2e[t];
    int e = 0;
    for (; e + 4 <= nE; e += 4) {
        float g0 = xe[(size_t)idxE[e] * EMB + t];
        float g1 = xe[(size_t)idxE[e + 1] * EMB + t];
        float g2 = xe[(size_t)idxE[e + 2] * EMB + t];
        float g3 = xe[(size_t)idxE[e + 3] * EMB + t];
        aE += valE[e] * g0 + valE[e + 1] * g1 + valE[e + 2] * g2 + valE[e + 3] * g3;
    }
    for (; e < nE; e++) aE += valE[e] * xe[(size_t)idxE[e] * EMB + t];
    float aD = b2d[t];
    e = 0;
    for (; e + 4 <= nD; e += 4) {
        float g0 = xd[(size_t)idxD[e] * EMB + t];
        float g1 = xd[(size_t)idxD[e + 1] * EMB + t];
        float g2 = xd[(size_t)idxD[e + 2] * EMB + t];
        float g3 = xd[(size_t)idxD[e + 3] * EMB + t];
        aD += valD[e] * g0 + valD[e + 1] * g1 + valD[e + 2] * g2 + valD[e + 3] * g3;
    }
    for (; e < nD; e++) aD += valD[e] * xd[(size_t)idxD[e] * EMB + t];
    float dmv = aE - inter[0] * aD;
    dm[(size_t)i * EMB + t] = dmv;
    float s = block_sum_256(dmv * feat[63 * EMB + t], red);
    if (t == 0) sdm[i] = s;
}

// K7: softmax over 4000 (in-place safe)
__global__ void k_softmax4000(const float* __restrict__ s, float* __restrict__ out) {
    __shared__ float red[256];
    int t = threadIdx.x;
    float m = -1e30f;
    for (int i = t; i < VMED; i += 256) m = fmaxf(m, s[i]);
    m = block_max_256(m, red);
    float sum = 0;
    for (int i = t; i < VMED; i += 256) { float e = __expf(s[i] - m); out[i] = e; sum += e; }
    sum = block_sum_256(sum, red);
    float inv = 1.f / sum;
    for (int i = t; i < VMED; i += 256) out[i] *= inv;
}

// K8: partials of fact1 = key_w1 @ dm, fact2 = w_med @ dm. 40 blocks x 100 rows.
__global__ void k_facts_part(const float* __restrict__ dm, const float* __restrict__ kw,
                             const float* __restrict__ wm, float* __restrict__ part1,
                             float* __restrict__ part2) {
    int f = threadIdx.x, b = blockIdx.x;
    int r0 = b * 100;
    float a1 = 0, a2 = 0;
    for (int r = r0; r < r0 + 100; r++) {
        float d = dm[(size_t)r * EMB + f];
        a1 += kw[r] * d;
        a2 += wm[r] * d;
    }
    part1[b * EMB + f] = a1;
    part2[b * EMB + f] = a2;
}

// K9: K-partitioned hidden matvec (48 blocks x 16 e-rows of out_w1)
__global__ void k_hidden_part(const float* __restrict__ feat, const float* __restrict__ part1,
                              const float* __restrict__ part2, const float* __restrict__ w1,
                              float* __restrict__ hpart) {
    __shared__ float xs[16];
    int b = blockIdx.x, t = threadIdx.x;
    int e0 = b * 16;
    if (t < 16) {
        int e = e0 + t;
        float xv;
        if (e < 256) xv = feat[63 * EMB + e];
        else if (e < 512) { float s = 0; for (int p = 0; p < 40; p++) s += part1[p * EMB + (e - 256)]; xv = s; }
        else              { float s = 0; for (int p = 0; p < 40; p++) s += part2[p * EMB + (e - 512)]; xv = s; }
        xs[t] = xv;
    }
    __syncthreads();
    float a1 = 0, a2 = 0;
    #pragma unroll
    for (int i = 0; i < 16; i++) {
        int e = e0 + i;
        a1 += xs[i] * w1[e * 512 + t];
        a2 += xs[i] * w1[e * 512 + t + 256];
    }
    hpart[b * 512 + t] = a1;
    hpart[b * 512 + t + 256] = a2;
}

// K10: hidden = relu(sum hpart + b1); result = hidden @ out_w2 + out_b2; sp = sigmoid.
__global__ void k_result(const float* __restrict__ hpart, const float* __restrict__ b1,
                         const float* __restrict__ w2, const float* __restrict__ b2,
                         float* __restrict__ out, float* __restrict__ sp) {
    __shared__ float hx[512];
    __shared__ float red[8][32];
    int t = threadIdx.x;
    for (int jj = t; jj < 512; jj += 256) {
        float s = b1[jj];
        for (int p = 0; p < 48; p++) s += hpart[p * 512 + jj];
        hx[jj] = s > 0.f ? s : 0.f;
    }
    __syncthreads();
    int lane = t & 31, seg = t >> 5;
    int j = blockIdx.x * 32 + lane;
    float acc = 0;
    int e0 = seg * 64;
    #pragma unroll 8
    for (int e = e0; e < e0 + 64; e++) acc += hx[e] * w2[(size_t)e * VMED + j];
    red[seg][lane] = acc;
    __syncthreads();
    if (seg == 0) {
        float s = b2[j];
        for (int p = 0; p < 8; p++) s += red[p][lane];
        out[j] = s;
        sp[j] = 1.f / (1.f + __expf(-s));
    }
}

// K11: bpart[i] = sp[i] * (ddi_raw[i,:] . sp) -- 8 rows per block accumulated
// in registers per iteration (32 independent loads in flight), one fused
// cross-row LDS reduction at the end.
__global__ void k_bneg(const float* __restrict__ ddi, const float* __restrict__ sp,
                       float* __restrict__ bpart) {
    __shared__ float4 spl[VMED / 4];
    __shared__ float red[8][256];
    int t = threadIdx.x;
    const float4* sp4 = (const float4*)sp;
    for (int j4 = t; j4 < VMED / 4; j4 += 256) spl[j4] = sp4[j4];
    __syncthreads();
    int i0 = blockIdx.x * 8;
    const float4* row4 = (const float4*)(ddi + (size_t)i0 * VMED);
    float p[8] = {0, 0, 0, 0, 0, 0, 0, 0};
    for (int j4 = t; j4 < VMED / 4; j4 += 256) {
        float4 s4 = spl[j4];
        #pragma unroll
        for (int rr = 0; rr < 8; rr++) {
            float4 a = row4[rr * (VMED / 4) + j4];
            p[rr] += a.x * s4.x + a.y * s4.y + a.z * s4.z + a.w * s4.w;
        }
    }
    #pragma unroll
    for (int rr = 0; rr < 8; rr++) red[rr][t] = p[rr];
    __syncthreads();
    for (int s = 128; s > 0; s >>= 1) {
        if (t < s) {
            #pragma unroll
            for (int rr = 0; rr < 8; rr++) red[rr][t] += red[rr][t + s];
        }
        __syncthreads();
    }
    if (t < 8) bpart[i0 + t] = sp[i0 + t] * red[t][0];
}

// K12: batch_neg = 0.0005 * sum(bpart) -> out[4000]
__global__ void FastRx_wo_Diag_19473381720179_kernel(const float* __restrict__ bpart,
                                                     float* __restrict__ out) {
    __shared__ float red[256];
    int t = threadIdx.x;
    float s = 0;
    for (int i = t; i < VMED; i += 256) s += bpart[i];
    s = block_sum_256(s, red);
    if (t == 0) out[VMED] = 0.0005f * s;
}

extern "C" __attribute__((visibility("default")))
void kernel_launch(void* const* d_in, const int* in_sizes, int n_in,
                   void* d_out, int out_size, void* d_ws, size_t ws_size,
                   hipStream_t stream) {
    const int*   proc_codes = (const int*)d_in[0];
    const int*   med_codes  = (const int*)d_in[1];
    const float* emb_table  = (const float*)d_in[2];
    const float* conv_w     = (const float*)d_in[3];
    const float* conv_b     = (const float*)d_in[4];
    const float* wq         = (const float*)d_in[5];
    const float* wk         = (const float*)d_in[6];
    const float* wv         = (const float*)d_in[7];
    const float* wr         = (const float*)d_in[8];
    const float* alpha      = (const float*)d_in[9];
    const float* beta       = (const float*)d_in[10];
    const float* ehr_adj    = (const float*)d_in[11];
    const float* ddi_adj    = (const float*)d_in[12];
    const float* ddi_raw    = (const float*)d_in[13];
    const float* ehr_w1     = (const float*)d_in[14];
    const float* ehr_b1     = (const float*)d_in[15];
    const float* ehr_w2     = (const float*)d_in[16];
    const float* ehr_b2     = (const float*)d_in[17];
    const float* ddi_w1     = (const float*)d_in[18];
    const float* ddi_b1     = (const float*)d_in[19];
    const float* ddi_w2     = (const float*)d_in[20];
    const float* ddi_b2     = (const float*)d_in[21];
    const float* inter      = (const float*)d_in[22];
    const float* out_w1     = (const float*)d_in[23];
    const float* out_b1     = (const float*)d_in[24];
    const float* out_w2     = (const float*)d_in[25];
    const float* out_b2     = (const float*)d_in[26];
    float* out = (float*)d_out;   // fp32: result[4000] ++ batch_neg[1]

    float* w = (float*)d_ws;
    float* q      = w;                  // 16384
    float* k      = w + 16384;          // 16384
    float* v      = w + 32768;          // 16384
    float* tmpA   = w + 49152;          // 16384 (qaw)
    float* tmpB   = w + 65536;          // 16384 (pbw)
    float* feat   = w + 81920;          // 16384
    float* wmed   = w + 98304;          // 4096
    float* sdm    = w + 102400;         // 4096 (softmax in-place -> key_w1)
    float* sp     = w + 106496;         // 4096
    float* bufA   = w + 110592;         // 1,024,000 (t2 ehr)
    float* bufC   = bufA + 1024000;     // 1,024,000 (t2 ddi)
    float* bufB   = bufC + 1024000;     // 1,024,000 (dm)
    int*   ccntE  = (int*)(bufB + 1024000);   // 4096
    int*   cidxE  = ccntE + 4096;             // 512000
    float* cvalE  = (float*)(cidxE + 512000); // 512000
    int*   ccntD  = (int*)(cvalE + 512000);   // 4096
    int*   cidxD  = ccntD + 4096;             // 512000
    float* cvalD  = (float*)(cidxD + 512000); // 512000
    // aliases into dead bufA (first written AFTER last read of bufA in k_acc):
    float* part1  = bufA;               // 40*256
    float* part2  = bufA + 10240;       // 40*256
    float* hpart  = bufA + 20480;       // 48*512
    float* bpart  = bufA + 45056;       // 4096

    k_ff1<<<NV, EMB, 0, stream>>>(proc_codes, emb_table, conv_w, conv_b,
                                  wq, wk, wv, alpha, q, k, v, tmpA);
    k_pbw<<<NV, EMB, 0, stream>>>(tmpA, k, beta, tmpB);
    k_feat<<<NV, EMB, 0, stream>>>(tmpB, v, q, wr, feat);
    k_visitw_wmed<<<1, 256, 0, stream>>>(feat, med_codes, wmed);

    k_gcn<<<1000, 256, 0, stream>>>(ehr_adj, ddi_adj,
                                    ehr_w1, ehr_b1, ehr_w2,
                                    ddi_w1, ddi_b1, ddi_w2,
                                    bufA, bufC,
                                    ccntE, cidxE, cvalE, ccntD, cidxD, cvalD);
    k_acc<<<VMED, 256, 0, stream>>>(ccntE, cidxE, cvalE, ccntD, cidxD, cvalD,
                                    bufA, bufC, ehr_b2, ddi_b2, inter, feat,
                                    bufB, sdm);

    k_softmax4000<<<1, 256, 0, stream>>>(sdm, sdm);
    k_facts_part<<<40, 256, 0, stream>>>(bufB, sdm, wmed, part1, part2);
    k_hidden_part<<<48, 256, 0, stream>>>(feat, part1, part2, out_w1, hpart);
    k_result<<<125, 256, 0, stream>>>(hpart, out_b1, out_w2, out_b2, out, sp);
    k_bneg<<<VMED / 8, 256, 0, stream>>>(ddi_raw, sp, bpart);
    FastRx_wo_Diag_19473381720179_kernel<<<1, 256, 0, stream>>>(bpart, out);
}

// Round 14
// 409.071 us; speedup vs baseline: 1.5047x; 1.0384x over previous
//
#include <hip/hip_runtime.h>
#include <hip/hip_bf16.h>

#define NV 64
#define NP 32
#define NM 16
#define VMED 4000
#define EMB 256
#define EMBFF 128
#define CAP 128   // max cached nnz/row (mean ~41; verified in R10)
#define GR 4      // rows per k_gcn block (R14: 8->4 for 2x blocks/CU)

// NOTE (hard-won, rounds 0-7): ALL float inputs and the output are FP32.
// Misreading them as bf16 gives parity-dependent mantissa garbage.
// NOTE (R13): manual ILP (deep unroll, multi-slot atomics) in the scan REGRESSED
// (VALU + bank conflicts up, BW down). Keep the scan body simple; get MLP from
// occupancy (blocks/CU), not intra-wave pipelining.

__device__ __forceinline__ float block_sum_256(float v, float* red) {
    int t = threadIdx.x;
    red[t] = v; __syncthreads();
    for (int s = 128; s > 0; s >>= 1) { if (t < s) red[t] += red[t + s]; __syncthreads(); }
    float r = red[0]; __syncthreads();
    return r;
}
__device__ __forceinline__ float block_max_256(float v, float* red) {
    int t = threadIdx.x;
    red[t] = v; __syncthreads();
    for (int s = 128; s > 0; s >>= 1) { if (t < s) red[t] = fmaxf(red[t], red[t + s]); __syncthreads(); }
    float r = red[0]; __syncthreads();
    return r;
}

// K1: fused embed_conv + qkv. Block = one visit, 256 threads.
__global__ void k_ff1(const int* __restrict__ proc, const float* __restrict__ emb,
                      const float* __restrict__ cw, const float* __restrict__ cb,
                      const float* __restrict__ wq, const float* __restrict__ wk,
                      const float* __restrict__ wv, const float* __restrict__ alpha,
                      float* __restrict__ q, float* __restrict__ k, float* __restrict__ v,
                      float* __restrict__ qaw) {
    __shared__ float sm[EMBFF + 2];
    __shared__ float x[EMBFF];
    __shared__ float red[256];
    int vi = blockIdx.x, t = threadIdx.x;
    if (t < EMBFF) {
        float s = 0.f;
        for (int c = 0; c < NP; c++) s += emb[proc[vi * NP + c] * EMBFF + t];
        sm[t + 1] = s * (1.0f / NP);
    }
    if (t == 0) { sm[0] = 0.f; sm[EMBFF + 1] = 0.f; }
    __syncthreads();
    if (t < EMBFF) {
        float o = cw[0] * sm[t] + cw[1] * sm[t + 1] + cw[2] * sm[t + 2] + cb[0];
        x[t] = o > 0.f ? o : 0.f;
    }
    __syncthreads();
    float aq = 0, ak = 0, av = 0;
    for (int e = 0; e < EMBFF; e++) {
        float xe = x[e];
        aq += xe * wq[e * EMB + t];
        ak += xe * wk[e * EMB + t];
        av += xe * wv[e * EMB + t];
    }
    q[vi * EMB + t] = aq; k[vi * EMB + t] = ak; v[vi * EMB + t] = av;
    const float scale = 0.0625f;
    float z = aq * alpha[t] * scale;
    float m = block_max_256(z, red);
    float e_ = __expf(z - m);
    float sum = block_sum_256(e_, red);
    qaw[vi * EMB + t] = aq * (e_ / sum);
}

// K2: gq = colsum(qaw) inline; p = gq*k; pbw = p*softmax(p*beta*scale)
__global__ void k_pbw(const float* __restrict__ qaw, const float* __restrict__ k,
                      const float* __restrict__ beta, float* __restrict__ pbw) {
    __shared__ float red[256];
    int vi = blockIdx.x, f = threadIdx.x;
    float g = 0;
    for (int r = 0; r < NV; r++) g += qaw[r * EMB + f];
    float p = g * k[vi * EMB + f];
    const float scale = 0.0625f;
    float z = p * beta[f] * scale;
    float m = block_max_256(z, red);
    float e_ = __expf(z - m);
    float sum = block_sum_256(e_, red);
    pbw[vi * EMB + f] = p * (e_ / sum);
}

// K3: gk = colsum(pbw) inline; feat = (gk*v) @ wr + q
__global__ void k_feat(const float* __restrict__ pbw, const float* __restrict__ v,
                       const float* __restrict__ q, const float* __restrict__ wr,
                       float* __restrict__ feat) {
    __shared__ float s[EMB];
    int vi = blockIdx.x, f = threadIdx.x;
    float g = 0;
    for (int r = 0; r < NV; r++) g += pbw[r * EMB + f];
    s[f] = g * v[vi * EMB + f];
    __syncthreads();
    float acc = 0;
    for (int e = 0; e < EMB; e++) acc += s[e] * wr[e * EMB + f];
    feat[vi * EMB + f] = acc + q[vi * EMB + f];
}

// K4: visit_w = softmax(query @ hist.T); w_med = visit_w @ hv (SET dedup)
__global__ void k_visitw_wmed(const float* __restrict__ feat, const int* __restrict__ med,
                              float* __restrict__ w_med) {
    __shared__ float qs[EMB];
    __shared__ float vw[64];
    __shared__ float red[256];
    __shared__ float wm[VMED];
    int t = threadIdx.x;
    for (int e = t; e < EMB; e += 256) qs[e] = feat[63 * EMB + e];
    for (int i = t; i < VMED; i += 256) wm[i] = 0.f;
    __syncthreads();
    float sc = -1e30f;
    if (t < 63) {
        float a = 0;
        for (int e = 0; e < EMB; e++) a += qs[e] * feat[t * EMB + e];
        sc = a;
    }
    float m = block_max_256(sc, red);
    float e_ = (t < 63) ? __expf(sc - m) : 0.f;
    float sum = block_sum_256(e_, red);
    if (t < 63) vw[t] = e_ / sum;
    __syncthreads();
    for (int i = t; i < 63 * NM; i += 256) {
        int vv = i / NM, mm = i % NM;
        int code = med[vv * NM + mm];
        bool dup = false;
        for (int m2 = 0; m2 < mm; m2++)
            if (med[vv * NM + m2] == code) dup = true;
        if (!dup) atomicAdd(&wm[code], vw[vv]);  // LDS atomic
    }
    __syncthreads();
    for (int i = t; i < VMED; i += 256) w_med[i] = wm[i];
}

// K5: fused GCN front-half, BOTH graphs. GR=4 rows/block, 2000 blocks
// (~8 blocks/CU -> ~32 waves/CU). Simple one-pass scan (R12 form), then
// h = relu(adj@w1+b1), then GR-row h@w2.
__global__ void k_gcn(const float* __restrict__ eadj, const float* __restrict__ dadj,
                      const float* __restrict__ ew1, const float* __restrict__ eb1,
                      const float* __restrict__ ew2,
                      const float* __restrict__ dw1, const float* __restrict__ db1,
                      const float* __restrict__ dw2,
                      float* __restrict__ outE, float* __restrict__ outD,
                      int* __restrict__ ccntE, int* __restrict__ cidxE, float* __restrict__ cvalE,
                      int* __restrict__ ccntD, int* __restrict__ cidxD, float* __restrict__ cvalD) {
    __shared__ float x[GR][EMB];
    __shared__ int idx[GR][CAP];
    __shared__ float val[GR][CAP];
    __shared__ int cnt[GR];
    int b = blockIdx.x, t = threadIdx.x;
    bool isD = b >= 1000;
    const float* adj = isD ? dadj : eadj;
    const float* w1  = isD ? dw1  : ew1;
    const float* b1  = isD ? db1  : eb1;
    const float* w2  = isD ? dw2  : ew2;
    float* outp = isD ? outD : outE;
    int*   ccnt = isD ? ccntD : ccntE;
    int*   cidx = isD ? cidxD : cidxE;
    float* cval = isD ? cvalD : cvalE;
    int r0 = (isD ? b - 1000 : b) * GR;
    if (t < GR) cnt[t] = 0;
    __syncthreads();

    const float4* base4 = (const float4*)(adj + (size_t)r0 * VMED);
    const int Q = VMED / 4;       // 1000 float4 per row
    for (int jj = t; jj < GR * Q; jj += 256) {
        float4 a = base4[jj];
        int r = jj / Q;           // magic-mul
        int c0 = (jj - r * Q) * 4;
        if (a.x != 0.f) { int p = atomicAdd(&cnt[r], 1); if (p < CAP) { idx[r][p] = c0;     val[r][p] = a.x; } }
        if (a.y != 0.f) { int p = atomicAdd(&cnt[r], 1); if (p < CAP) { idx[r][p] = c0 + 1; val[r][p] = a.y; } }
        if (a.z != 0.f) { int p = atomicAdd(&cnt[r], 1); if (p < CAP) { idx[r][p] = c0 + 2; val[r][p] = a.z; } }
        if (a.w != 0.f) { int p = atomicAdd(&cnt[r], 1); if (p < CAP) { idx[r][p] = c0 + 3; val[r][p] = a.w; } }
    }
    __syncthreads();

    for (int r = 0; r < GR; r++) {
        int n = cnt[r] < CAP ? cnt[r] : CAP;
        if (t == 0) ccnt[r0 + r] = n;
        if (t < n) { cidx[(r0 + r) * CAP + t] = idx[r][t]; cval[(r0 + r) * CAP + t] = val[r][t]; }
        float acc = b1[t];
        for (int e = 0; e < n; e++) acc += val[r][e] * w1[(size_t)idx[r][e] * EMB + t];
        x[r][t] = acc > 0.f ? acc : 0.f;
    }
    __syncthreads();

    float a[GR];
    #pragma unroll
    for (int r = 0; r < GR; r++) a[r] = 0.f;
    #pragma unroll 4
    for (int e = 0; e < EMB; e++) {
        float we = w2[e * EMB + t];
        #pragma unroll
        for (int r = 0; r < GR; r++) a[r] += x[r][e] * we;
    }
    for (int r = 0; r < GR; r++) outp[(size_t)(r0 + r) * EMB + t] = a[r];
}

// K6: dm = (ehr@xe + eb2) - inter*(ddi@xd + db2) via cached CSRs (separate LDS
// buffers, one barrier); fused sdm[i] = dot(query, dm[i]).
__global__ void k_acc(const int* __restrict__ ccntE, const int* __restrict__ cidxE,
                      const float* __restrict__ cvalE,
                      const int* __restrict__ ccntD, const int* __restrict__ cidxD,
                      const float* __restrict__ cvalD,
                      const float* __restrict__ xe, const float* __restrict__ xd,
                      const float* __restrict__ b2e, const float* __restrict__ b2d,
                      const float* __restrict__ inter, const float* __restrict__ feat,
                      float* __restrict__ dm, float* __restrict__ sdm) {
    __shared__ int idxE[CAP];
    __shared__ float valE[CAP];
    __shared__ int idxD[CAP];
    __shared__ float valD[CAP];
    __shared__ float red[256];
    int i = blockIdx.x, t = threadIdx.x;
    int nE = ccntE[i], nD = ccntD[i];
    if (t < nE) { idxE[t] = cidxE[i * CAP + t]; valE[t] = cvalE[i * CAP + t]; }
    if (t < nD) { idxD[t] = cidxD[i * CAP + t]; valD[t] = cvalD[i * CAP + t]; }
    __syncthreads();
    float aE = b2e[t];
    for (int e = 0; e < nE; e++) aE += valE[e] * xe[(size_t)idxE[e] * EMB + t];
    float aD = b2d[t];
    for (int e = 0; e < nD; e++) aD += valD[e] * xd[(size_t)idxD[e] * EMB + t];
    float dmv = aE - inter[0] * aD;
    dm[(size_t)i * EMB + t] = dmv;
    float s = block_sum_256(dmv * feat[63 * EMB + t], red);
    if (t == 0) sdm[i] = s;
}

// K7: softmax over 4000 (in-place safe)
__global__ void k_softmax4000(const float* __restrict__ s, float* __restrict__ out) {
    __shared__ float red[256];
    int t = threadIdx.x;
    float m = -1e30f;
    for (int i = t; i < VMED; i += 256) m = fmaxf(m, s[i]);
    m = block_max_256(m, red);
    float sum = 0;
    for (int i = t; i < VMED; i += 256) { float e = __expf(s[i] - m); out[i] = e; sum += e; }
    sum = block_sum_256(sum, red);
    float inv = 1.f / sum;
    for (int i = t; i < VMED; i += 256) out[i] *= inv;
}

// K8: partials of fact1 = key_w1 @ dm, fact2 = w_med @ dm. 40 blocks x 100 rows.
__global__ void k_facts_part(const float* __restrict__ dm, const float* __restrict__ kw,
                             const float* __restrict__ wm, float* __restrict__ part1,
                             float* __restrict__ part2) {
    int f = threadIdx.x, b = blockIdx.x;
    int r0 = b * 100;
    float a1 = 0, a2 = 0;
    for (int r = r0; r < r0 + 100; r++) {
        float d = dm[(size_t)r * EMB + f];
        a1 += kw[r] * d;
        a2 += wm[r] * d;
    }
    part1[b * EMB + f] = a1;
    part2[b * EMB + f] = a2;
}

// K9: K-partitioned hidden matvec (48 blocks x 16 e-rows of out_w1)
__global__ void k_hidden_part(const float* __restrict__ feat, const float* __restrict__ part1,
                              const float* __restrict__ part2, const float* __restrict__ w1,
                              float* __restrict__ hpart) {
    __shared__ float xs[16];
    int b = blockIdx.x, t = threadIdx.x;
    int e0 = b * 16;
    if (t < 16) {
        int e = e0 + t;
        float xv;
        if (e < 256) xv = feat[63 * EMB + e];
        else if (e < 512) { float s = 0; for (int p = 0; p < 40; p++) s += part1[p * EMB + (e - 256)]; xv = s; }
        else              { float s = 0; for (int p = 0; p < 40; p++) s += part2[p * EMB + (e - 512)]; xv = s; }
        xs[t] = xv;
    }
    __syncthreads();
    float a1 = 0, a2 = 0;
    #pragma unroll
    for (int i = 0; i < 16; i++) {
        int e = e0 + i;
        a1 += xs[i] * w1[e * 512 + t];
        a2 += xs[i] * w1[e * 512 + t + 256];
    }
    hpart[b * 512 + t] = a1;
    hpart[b * 512 + t + 256] = a2;
}

// K10: hidden = relu(sum hpart + b1); result = hidden @ out_w2 + out_b2; sp = sigmoid.
__global__ void k_result(const float* __restrict__ hpart, const float* __restrict__ b1,
                         const float* __restrict__ w2, const float* __restrict__ b2,
                         float* __restrict__ out, float* __restrict__ sp) {
    __shared__ float hx[512];
    __shared__ float red[8][32];
    int t = threadIdx.x;
    for (int jj = t; jj < 512; jj += 256) {
        float s = b1[jj];
        for (int p = 0; p < 48; p++) s += hpart[p * 512 + jj];
        hx[jj] = s > 0.f ? s : 0.f;
    }
    __syncthreads();
    int lane = t & 31, seg = t >> 5;
    int j = blockIdx.x * 32 + lane;
    float acc = 0;
    int e0 = seg * 64;
    #pragma unroll 8
    for (int e = e0; e < e0 + 64; e++) acc += hx[e] * w2[(size_t)e * VMED + j];
    red[seg][lane] = acc;
    __syncthreads();
    if (seg == 0) {
        float s = b2[j];
        for (int p = 0; p < 8; p++) s += red[p][lane];
        out[j] = s;
        sp[j] = 1.f / (1.f + __expf(-s));
    }
}

// K11: bpart[i] = sp[i] * (ddi_raw[i,:] . sp) -- 8 rows/block in registers,
// one fused cross-row LDS reduction.
__global__ void k_bneg(const float* __restrict__ ddi, const float* __restrict__ sp,
                       float* __restrict__ bpart) {
    __shared__ float4 spl[VMED / 4];
    __shared__ float red[8][256];
    int t = threadIdx.x;
    const float4* sp4 = (const float4*)sp;
    for (int j4 = t; j4 < VMED / 4; j4 += 256) spl[j4] = sp4[j4];
    __syncthreads();
    int i0 = blockIdx.x * 8;
    const float4* row4 = (const float4*)(ddi + (size_t)i0 * VMED);
    float p[8] = {0, 0, 0, 0, 0, 0, 0, 0};
    for (int j4 = t; j4 < VMED / 4; j4 += 256) {
        float4 s4 = spl[j4];
        #pragma unroll
        for (int rr = 0; rr < 8; rr++) {
            float4 a = row4[rr * (VMED / 4) + j4];
            p[rr] += a.x * s4.x + a.y * s4.y + a.z * s4.z + a.w * s4.w;
        }
    }
    #pragma unroll
    for (int rr = 0; rr < 8; rr++) red[rr][t] = p[rr];
    __syncthreads();
    for (int s = 128; s > 0; s >>= 1) {
        if (t < s) {
            #pragma unroll
            for (int rr = 0; rr < 8; rr++) red[rr][t] += red[rr][t + s];
        }
        __syncthreads();
    }
    if (t < 8) bpart[i0 + t] = sp[i0 + t] * red[t][0];
}

// K12: batch_neg = 0.0005 * sum(bpart) -> out[4000]
__global__ void FastRx_wo_Diag_19473381720179_kernel(const float* __restrict__ bpart,
                                                     float* __restrict__ out) {
    __shared__ float red[256];
    int t = threadIdx.x;
    float s = 0;
    for (int i = t; i < VMED; i += 256) s += bpart[i];
    s = block_sum_256(s, red);
    if (t == 0) out[VMED] = 0.0005f * s;
}

extern "C" __attribute__((visibility("default")))
void kernel_launch(void* const* d_in, const int* in_sizes, int n_in,
                   void* d_out, int out_size, void* d_ws, size_t ws_size,
                   hipStream_t stream) {
    const int*   proc_codes = (const int*)d_in[0];
    const int*   med_codes  = (const int*)d_in[1];
    const float* emb_table  = (const float*)d_in[2];
    const float* conv_w     = (const float*)d_in[3];
    const float* conv_b     = (const float*)d_in[4];
    const float* wq         = (const float*)d_in[5];
    const float* wk         = (const float*)d_in[6];
    const float* wv         = (const float*)d_in[7];
    const float* wr         = (const float*)d_in[8];
    const float* alpha      = (const float*)d_in[9];
    const float* beta       = (const float*)d_in[10];
    const float* ehr_adj    = (const float*)d_in[11];
    const float* ddi_adj    = (const float*)d_in[12];
    const float* ddi_raw    = (const float*)d_in[13];
    const float* ehr_w1     = (const float*)d_in[14];
    const float* ehr_b1     = (const float*)d_in[15];
    const float* ehr_w2     = (const float*)d_in[16];
    const float* ehr_b2     = (const float*)d_in[17];
    const float* ddi_w1     = (const float*)d_in[18];
    const float* ddi_b1     = (const float*)d_in[19];
    const float* ddi_w2     = (const float*)d_in[20];
    const float* ddi_b2     = (const float*)d_in[21];
    const float* inter      = (const float*)d_in[22];
    const float* out_w1     = (const float*)d_in[23];
    const float* out_b1     = (const float*)d_in[24];
    const float* out_w2     = (const float*)d_in[25];
    const float* out_b2     = (const float*)d_in[26];
    float* out = (float*)d_out;   // fp32: result[4000] ++ batch_neg[1]

    float* w = (float*)d_ws;
    float* q      = w;                  // 16384
    float* k      = w + 16384;          // 16384
    float* v      = w + 32768;          // 16384
    float* tmpA   = w + 49152;          // 16384 (qaw)
    float* tmpB   = w + 65536;          // 16384 (pbw)
    float* feat   = w + 81920;          // 16384
    float* wmed   = w + 98304;          // 4096
    float* sdm    = w + 102400;         // 4096 (softmax in-place -> key_w1)
    float* sp     = w + 106496;         // 4096
    float* bufA   = w + 110592;         // 1,024,000 (t2 ehr)
    float* bufC   = bufA + 1024000;     // 1,024,000 (t2 ddi)
    float* bufB   = bufC + 1024000;     // 1,024,000 (dm)
    int*   ccntE  = (int*)(bufB + 1024000);   // 4096
    int*   cidxE  = ccntE + 4096;             // 512000
    float* cvalE  = (float*)(cidxE + 512000); // 512000
    int*   ccntD  = (int*)(cvalE + 512000);   // 4096
    int*   cidxD  = ccntD + 4096;             // 512000
    float* cvalD  = (float*)(cidxD + 512000); // 512000
    // aliases into dead bufA (first written AFTER last read of bufA in k_acc):
    float* part1  = bufA;               // 40*256
    float* part2  = bufA + 10240;       // 40*256
    float* hpart  = bufA + 20480;       // 48*512
    float* bpart  = bufA + 45056;       // 4096

    k_ff1<<<NV, EMB, 0, stream>>>(proc_codes, emb_table, conv_w, conv_b,
                                  wq, wk, wv, alpha, q, k, v, tmpA);
    k_pbw<<<NV, EMB, 0, stream>>>(tmpA, k, beta, tmpB);
    k_feat<<<NV, EMB, 0, stream>>>(tmpB, v, q, wr, feat);
    k_visitw_wmed<<<1, 256, 0, stream>>>(feat, med_codes, wmed);

    k_gcn<<<2000, 256, 0, stream>>>(ehr_adj, ddi_adj,
                                    ehr_w1, ehr_b1, ehr_w2,
                                    ddi_w1, ddi_b1, ddi_w2,
                                    bufA, bufC,
                                    ccntE, cidxE, cvalE, ccntD, cidxD, cvalD);
    k_acc<<<VMED, 256, 0, stream>>>(ccntE, cidxE, cvalE, ccntD, cidxD, cvalD,
                                    bufA, bufC, ehr_b2, ddi_b2, inter, feat,
                                    bufB, sdm);

    k_softmax4000<<<1, 256, 0, stream>>>(sdm, sdm);
    k_facts_part<<<40, 256, 0, stream>>>(bufB, sdm, wmed, part1, part2);
    k_hidden_part<<<48, 256, 0, stream>>>(feat, part1, part2, out_w1, hpart);
    k_result<<<125, 256, 0, stream>>>(hpart, out_b1, out_w2, out_b2, out, sp);
    k_bneg<<<VMED / 8, 256, 0, stream>>>(ddi_raw, sp, bpart);
    FastRx_wo_Diag_19473381720179_kernel<<<1, 256, 0, stream>>>(bpart, out);
}